// Round 8
// baseline (319.700 us; speedup 1.0000x reference)
//
#include <hip/hip_runtime.h>
#include <hip/hip_bf16.h>

// Problem constants
#define B_    8
#define F_    16
#define NP_   196
#define SEQ_  3137        // 1 + F_*NP_
#define H_    8
#define DH_   64
#define BH_   64          // B_*H_
#define M_    25096       // B_*SEQ_
#define MPAD_ 25216       // storage pad (197*128)
#define DIM_  512
#define NQKV_ 1536

typedef _Float16 half8_t __attribute__((ext_vector_type(8)));
typedef _Float16 half4_t __attribute__((ext_vector_type(4)));
typedef float f32x4 __attribute__((ext_vector_type(4)));

// workspace byte offsets
#define XH_OFF     ((size_t)0)                    // [MPAD_][512] f16   25,821,184
#define WQKVT_OFF  ((size_t)25821184)             // [1536][512] f16     1,572,864
#define WOUTT_OFF  ((size_t)27394048)             // [512][512]  f16       524,288
#define QH_OFF     ((size_t)27918336)             // [64][3137][64] f16 25,698,304
#define KH_OFF     ((size_t)53616640)
#define VH_OFF     ((size_t)79314944)
#define ATTNH_OFF  ((size_t)105013248)            // [MPAD_][512] f16   25,821,184

__device__ __forceinline__ void load_lds16(const _Float16* g, _Float16* l) {
  __builtin_amdgcn_global_load_lds(
      (const __attribute__((address_space(1))) void*)g,
      (__attribute__((address_space(3))) void*)l, 16, 0, 0);
}

// bijective XCD-chunk swizzle (m204)
__device__ __forceinline__ int xcd_swz(int orig, int nwg) {
  int q = nwg >> 3, r = nwg & 7;
  int x = orig & 7, j = orig >> 3;
  return (x < r ? x * (q + 1) : r * (q + 1) + (x - r) * q) + j;
}

// ---------------------------------------------------------------------------
// conversion kernels
// ---------------------------------------------------------------------------
__global__ __launch_bounds__(256) void convert_x_kernel(
    const float* __restrict__ x, _Float16* __restrict__ xh) {
  const size_t n8 = (size_t)M_ * DIM_ / 8;
  for (size_t i = (size_t)blockIdx.x * blockDim.x + threadIdx.x; i < n8;
       i += (size_t)gridDim.x * blockDim.x) {
    float4 a = ((const float4*)x)[2 * i];
    float4 b = ((const float4*)x)[2 * i + 1];
    half8_t h;
    h[0] = (_Float16)a.x; h[1] = (_Float16)a.y; h[2] = (_Float16)a.z; h[3] = (_Float16)a.w;
    h[4] = (_Float16)b.x; h[5] = (_Float16)b.y; h[6] = (_Float16)b.z; h[7] = (_Float16)b.w;
    ((half8_t*)xh)[i] = h;
  }
}

// both weights: [512][C] fp32 -> [C][512] fp16 in one launch
__global__ __launch_bounds__(256) void transpose_conv2_kernel(
    const float* __restrict__ wqkv, _Float16* __restrict__ wqkvT,
    const float* __restrict__ wout, _Float16* __restrict__ woutT) {
  __shared__ float tile[32][33];
  int by = blockIdx.y;
  const float* in; _Float16* out; int C;
  if (by < 48) { in = wqkv; out = wqkvT; C = NQKV_; }
  else         { in = wout; out = woutT; C = DIM_;  by -= 48; }
  const int r0 = blockIdx.x * 32, c0 = by * 32;
  const int lr = threadIdx.x >> 5, lc = threadIdx.x & 31;
#pragma unroll
  for (int p = 0; p < 4; ++p) {
    int r = p * 8 + lr;
    tile[r][lc] = in[(size_t)(r0 + r) * C + c0 + lc];
  }
  __syncthreads();
#pragma unroll
  for (int p = 0; p < 4; ++p) {
    int rr = p * 8 + lr;
    out[(size_t)(c0 + rr) * DIM_ + r0 + lc] = (_Float16)tile[lc][rr];
  }
}

// ---------------------------------------------------------------------------
// shared f16 MFMA mainloop: 128x128 tile, BK=64, 256 threads (4 waves 2x2).
// LDS XOR-swizzled: linear global_load_lds dest + pre-swizzled global source
// col; frag reads XOR (row&7)<<3.
// ---------------------------------------------------------------------------
__device__ __forceinline__ void gemm_mainloop_f16(
    const _Float16* __restrict__ A, const _Float16* __restrict__ Bt,
    int m0, int n0, _Float16* As, _Float16* Bs, f32x4 acc[4][4]) {
  const int tid = threadIdx.x;
  const int w = tid >> 6, lane = tid & 63;
  const int wr = w >> 1, wc = w & 1;
  const int lrow = lane & 15;
  const int g = lane >> 4;
  const int sw = lane & 7;

  const int srow = lane >> 3;
  const int scol = ((lane & 7) ^ srow) << 3;

  for (int k0 = 0; k0 < DIM_; k0 += 64) {
#pragma unroll
    for (int i = 0; i < 4; ++i) {
      int c = w * 4 + i;
      int r = c * 8 + srow;
      load_lds16(A + (size_t)(m0 + r) * DIM_ + k0 + scol, As + c * 512);
      load_lds16(Bt + (size_t)(n0 + r) * DIM_ + k0 + scol, Bs + c * 512);
    }
    __syncthreads();

#pragma unroll
    for (int kk = 0; kk < 2; ++kk) {
      const int kf = ((kk * 4 + g) ^ sw) << 3;
      half8_t a[4], b[4];
#pragma unroll
      for (int m = 0; m < 4; ++m)
        a[m] = *(const half8_t*)(As + (wr * 64 + m * 16 + lrow) * 64 + kf);
#pragma unroll
      for (int n = 0; n < 4; ++n)
        b[n] = *(const half8_t*)(Bs + (wc * 64 + n * 16 + lrow) * 64 + kf);
#pragma unroll
      for (int m = 0; m < 4; ++m)
#pragma unroll
        for (int n = 0; n < 4; ++n)
          acc[m][n] = __builtin_amdgcn_mfma_f32_16x16x32_f16(a[m], b[n], acc[m][n], 0, 0, 0);
    }
    __syncthreads();
  }
}

// ---------------------------------------------------------------------------
// K1: qkv = xh @ WqkvT^T, scatter into qh/kh/vh [bh][t][64] f16, q scaled.
// Staged coalesced epilogue (LDS transpose, 128B row stores).
// ---------------------------------------------------------------------------
__global__ __launch_bounds__(256) void qkv_gemm_kernel(
    const _Float16* __restrict__ xh, const _Float16* __restrict__ wqkvT,
    _Float16* __restrict__ qh, _Float16* __restrict__ kh, _Float16* __restrict__ vh) {
  __shared__ _Float16 As[128 * 64];
  __shared__ _Float16 Bs[128 * 64];
  const int nwg = 197 * 12;
  const int lin = xcd_swz(blockIdx.x, nwg);
  const int mb = lin / 12, nb = lin - mb * 12;
  const int m0 = mb * 128, n0 = nb * 128;

  f32x4 acc[4][4];
#pragma unroll
  for (int m = 0; m < 4; ++m)
#pragma unroll
    for (int n = 0; n < 4; ++n) acc[m][n] = (f32x4)0.f;

  gemm_mainloop_f16(xh, wqkvT, m0, n0, As, Bs, acc);
  // mainloop ends with __syncthreads(): safe to reuse As/Bs as staging.

  const int tid = threadIdx.x;
  const int w = tid >> 6, lane = tid & 63;
  const int wr = w >> 1, wc = w & 1;
  const int g = lane >> 4, lrow = lane & 15;

  _Float16* stg = (w < 2) ? (As + w * 4096) : (Bs + (w - 2) * 4096);
  const int gcb0 = n0 + wc * 64;            // 64-aligned -> one head chunk
  const int which = gcb0 >> 9;
  const int h = (gcb0 >> 6) & 7;
  const float scale = (which == 0) ? 0.125f : 1.0f;
  _Float16* dst = (which == 0) ? qh : (which == 1) ? kh : vh;

#pragma unroll
  for (int m = 0; m < 4; ++m)
#pragma unroll
    for (int n = 0; n < 4; ++n)
#pragma unroll
      for (int j = 0; j < 4; ++j) {
        int row = m * 16 + g * 4 + j;
        int col = n * 16 + lrow;
        int slot = (col >> 3) ^ (row & 7);
        stg[row * 64 + slot * 8 + (col & 7)] = (_Float16)(acc[m][n][j] * scale);
      }
  asm volatile("s_waitcnt lgkmcnt(0)" ::: "memory");
  __builtin_amdgcn_sched_barrier(0);

  const int rl = lane >> 3, cs = lane & 7;
#pragma unroll
  for (int rr = 0; rr < 8; ++rr) {
    int row = rr * 8 + rl;
    int grow = m0 + wr * 64 + row;
    if (grow < M_) {
      int b = grow / SEQ_;
      int t = grow - b * SEQ_;
      half8_t v = *(const half8_t*)(stg + row * 64 + ((cs ^ (row & 7)) << 3));
      *(half8_t*)(dst + ((size_t)(b * H_ + h) * SEQ_ + t) * DH_ + cs * 8) = v;
    }
  }
}

// ---------------------------------------------------------------------------
// K4: out = attnh @ WoutT^T + bout (fp32 out).
// ---------------------------------------------------------------------------
__global__ __launch_bounds__(256) void out_gemm_kernel(
    const _Float16* __restrict__ attnh, const _Float16* __restrict__ woutT,
    const float* __restrict__ bias, float* __restrict__ out) {
  __shared__ _Float16 As[128 * 64];
  __shared__ _Float16 Bs[128 * 64];
  const int nwg = 197 * 4;
  const int lin = xcd_swz(blockIdx.x, nwg);
  const int mb = lin >> 2, nb = lin & 3;
  const int m0 = mb * 128, n0 = nb * 128;

  f32x4 acc[4][4];
#pragma unroll
  for (int m = 0; m < 4; ++m)
#pragma unroll
    for (int n = 0; n < 4; ++n) acc[m][n] = (f32x4)0.f;

  gemm_mainloop_f16(attnh, woutT, m0, n0, As, Bs, acc);

  const int tid = threadIdx.x;
  const int w = tid >> 6, lane = tid & 63;
  const int wr = w >> 1, wc = w & 1;
#pragma unroll
  for (int n = 0; n < 4; ++n) {
    const int gcol = n0 + wc * 64 + n * 16 + (lane & 15);
    const float bv = bias[gcol];
#pragma unroll
    for (int m = 0; m < 4; ++m)
#pragma unroll
      for (int j = 0; j < 4; ++j) {
        int grow = m0 + wr * 64 + m * 16 + (lane >> 4) * 4 + j;
        if (grow < M_) out[(size_t)grow * DIM_ + gcol] = acc[m][n][j] + bv;
      }
  }
}

// ---------------------------------------------------------------------------
// K2+K3 fused attention. Blocks 0..63: CLS attention (one per (b,h)).
// Blocks 64..1087: frame attention (one per (bh, frame), 4 waves, MFMA).
// CLS aliases its LDS inside the frame path's 59 KB footprint.
// ---------------------------------------------------------------------------
__global__ __launch_bounds__(256) void attn_kernel(
    const _Float16* __restrict__ qh, const _Float16* __restrict__ kh,
    const _Float16* __restrict__ vh, _Float16* __restrict__ attnh) {
  __shared__ _Float16 VT[64 * 232];      // frame: V^T [d][key]
  __shared__ _Float16 Pb[4][16 * 232];   // frame: per-wave P [q][key]
  const int bx = blockIdx.x;
  const int tid = threadIdx.x;

  if (bx < BH_) {
    // ---------------- CLS attention (256 threads) ----------------
    const int bh = bx;
    const int b = bh >> 3, h = bh & 7;
    float* s   = (float*)VT;             // [SEQ_] (12.5 KB <= 29.7 KB)
    float* qs  = (float*)Pb;             // [64]
    float* red = qs + 64;                // [256]

    if (tid < 64) qs[tid] = (float)qh[(size_t)bh * SEQ_ * DH_ + tid];
    __syncthreads();

    float lmax = -1e30f;
    for (int j = tid; j < SEQ_; j += 256) {
      const half8_t* kr = (const half8_t*)(kh + ((size_t)bh * SEQ_ + j) * DH_);
      float sc = 0.f;
#pragma unroll
      for (int i = 0; i < 8; ++i) {
        half8_t kk = kr[i];
#pragma unroll
        for (int u = 0; u < 8; ++u) sc += qs[8 * i + u] * (float)kk[u];
      }
      s[j] = sc;
      lmax = fmaxf(lmax, sc);
    }
    red[tid] = lmax; __syncthreads();
    for (int st = 128; st > 0; st >>= 1) {
      if (tid < st) red[tid] = fmaxf(red[tid], red[tid + st]);
      __syncthreads();
    }
    float m = red[0]; __syncthreads();

    float lsum = 0.f;
    for (int j = tid; j < SEQ_; j += 256) {
      float p = __expf(s[j] - m);
      s[j] = p;
      lsum += p;
    }
    red[tid] = lsum; __syncthreads();
    for (int st = 128; st > 0; st >>= 1) {
      if (tid < st) red[tid] += red[tid + st];
      __syncthreads();
    }
    float l = red[0]; __syncthreads();

    const int d = tid & 63, c = tid >> 6;
    float a = 0.f;
    for (int j = c; j < SEQ_; j += 4)
      a += s[j] * (float)vh[((size_t)bh * SEQ_ + j) * DH_ + d];
    red[tid] = a; __syncthreads();
    if (tid < 64) {
      float o = (red[tid] + red[64 + tid] + red[128 + tid] + red[192 + tid]) / l;
      attnh[(size_t)(b * SEQ_) * DIM_ + h * DH_ + tid] = (_Float16)o;
    }
    return;
  }

  // ---------------- frame attention ----------------
  const int bxx = bx - BH_;
  const int bh = bxx >> 4, fi = bxx & 15;
  const int b = bh >> 3, h = bh & 7;
  const int w = tid >> 6, lane = tid & 63;
  const int g = lane >> 4, lc = lane & 15;
  _Float16* Pw = Pb[w];

  const size_t base = (size_t)bh * SEQ_ * DH_;

  // stage V^T (transpose-scatter), valid keys 0..196
  for (int item = tid; item < 197 * 8; item += 256) {
    int c8 = item / 197;
    int key = item - c8 * 197;
    int rowtok = (key == 0) ? 0 : fi * NP_ + key;
    half8_t hv = *(const half8_t*)(vh + base + (size_t)rowtok * DH_ + c8 * 8);
#pragma unroll
    for (int u = 0; u < 8; ++u) VT[(c8 * 8 + u) * 232 + key] = hv[u];
  }
  for (int idx = tid; idx < 64 * 35; idx += 256) {
    int d = idx / 35;
    VT[d * 232 + 197 + (idx - d * 35)] = (_Float16)0.f;
  }
#pragma unroll
  for (int z = 0; z < 4; ++z) {
    int idx = z * 64 + lane;
    Pw[(idx >> 4) * 232 + 208 + (idx & 15)] = (_Float16)0.f;
  }
  __syncthreads();

  const f32x4 zero4 = (f32x4)0.f;

  for (int qt = w; qt < 13; qt += 4) {
    int qq = qt * 16 + lc;
    int qtok = 1 + fi * NP_ + min(qq, NP_ - 1);
    const _Float16* qp = qh + base + (size_t)qtok * DH_ + g * 8;
    half8_t qb0 = *(const half8_t*)(qp);
    half8_t qb1 = *(const half8_t*)(qp + 32);

    f32x4 st[13];
#pragma unroll
    for (int t = 0; t < 13; ++t) {
      int key = t * 16 + lc;
      int rowtok = (key == 0) ? 0 : fi * NP_ + min(key, NP_);
      const _Float16* kp = kh + base + (size_t)rowtok * DH_ + g * 8;
      half8_t ka0 = *(const half8_t*)(kp);
      half8_t ka1 = *(const half8_t*)(kp + 32);
      st[t] = __builtin_amdgcn_mfma_f32_16x16x32_f16(ka0, qb0, zero4, 0, 0, 0);
      st[t] = __builtin_amdgcn_mfma_f32_16x16x32_f16(ka1, qb1, st[t], 0, 0, 0);
    }

    float mx = -1e30f;
#pragma unroll
    for (int t = 0; t < 13; ++t)
#pragma unroll
      for (int j = 0; j < 4; ++j) {
        int key = t * 16 + g * 4 + j;
        if (key >= 197) st[t][j] = -1e30f;
        mx = fmaxf(mx, st[t][j]);
      }
    mx = fmaxf(mx, __shfl_xor(mx, 16));
    mx = fmaxf(mx, __shfl_xor(mx, 32));
    float l = 0.f;
#pragma unroll
    for (int t = 0; t < 13; ++t)
#pragma unroll
      for (int j = 0; j < 4; ++j) {
        float p = __expf(st[t][j] - mx);
        st[t][j] = p;
        l += p;
      }
    l += __shfl_xor(l, 16);
    l += __shfl_xor(l, 32);
    const float inv = 1.f / l;

#pragma unroll
    for (int t = 0; t < 13; ++t) {
      half4_t hp;
#pragma unroll
      for (int j = 0; j < 4; ++j) hp[j] = (_Float16)(st[t][j] * inv);
      *(half4_t*)(Pw + lc * 232 + t * 16 + g * 4) = hp;
    }

    f32x4 o[4];
#pragma unroll
    for (int dt = 0; dt < 4; ++dt) o[dt] = zero4;
#pragma unroll
    for (int c = 0; c < 7; ++c) {
      half8_t pa = *(const half8_t*)(Pw + lc * 232 + c * 32 + g * 8);
#pragma unroll
      for (int dt = 0; dt < 4; ++dt) {
        half8_t vb = *(const half8_t*)(VT + (dt * 16 + lc) * 232 + c * 32 + g * 8);
        o[dt] = __builtin_amdgcn_mfma_f32_16x16x32_f16(pa, vb, o[dt], 0, 0, 0);
      }
    }

#pragma unroll
    for (int dt = 0; dt < 4; ++dt)
#pragma unroll
      for (int j = 0; j < 4; ++j) {
        int q = qt * 16 + g * 4 + j;
        if (q < NP_) {
          int tok = 1 + fi * NP_ + q;
          attnh[((size_t)(b * SEQ_) + tok) * DIM_ + h * DH_ + dt * 16 + lc] =
              (_Float16)o[dt][j];
        }
      }
  }
}

// ---------------------------------------------------------------------------
extern "C" void kernel_launch(void* const* d_in, const int* in_sizes, int n_in,
                              void* d_out, int out_size, void* d_ws, size_t ws_size,
                              hipStream_t stream) {
  (void)in_sizes; (void)n_in; (void)out_size; (void)ws_size;
  const float* x    = (const float*)d_in[0];
  const float* wqkv = (const float*)d_in[1];
  const float* wout = (const float*)d_in[2];
  const float* bout = (const float*)d_in[3];
  char* ws = (char*)d_ws;
  _Float16* xh    = (_Float16*)(ws + XH_OFF);
  _Float16* wqkvT = (_Float16*)(ws + WQKVT_OFF);
  _Float16* woutT = (_Float16*)(ws + WOUTT_OFF);
  _Float16* qh    = (_Float16*)(ws + QH_OFF);
  _Float16* kh    = (_Float16*)(ws + KH_OFF);
  _Float16* vh    = (_Float16*)(ws + VH_OFF);
  _Float16* attnh = (_Float16*)(ws + ATTNH_OFF);
  float* out = (float*)d_out;

  convert_x_kernel<<<2048, 256, 0, stream>>>(x, xh);
  {
    dim3 g(16, 64);  // 48 blocks-y for Wqkv, 16 for Wout
    transpose_conv2_kernel<<<g, 256, 0, stream>>>(wqkv, wqkvT, wout, woutT);
  }

  qkv_gemm_kernel<<<197 * 12, 256, 0, stream>>>(xh, wqkvT, qh, kh, vh);

  attn_kernel<<<BH_ + BH_ * F_, 256, 0, stream>>>(qh, kh, vh, attnh);

  out_gemm_kernel<<<197 * 4, 256, 0, stream>>>(attnh, woutT, bout, out);
}

// Round 9
// 206.382 us; speedup vs baseline: 1.5491x; 1.5491x over previous
//
#include <hip/hip_runtime.h>
#include <hip/hip_bf16.h>

// Problem constants
#define B_    8
#define F_    16
#define NP_   196
#define SEQ_  3137        // 1 + F_*NP_
#define H_    8
#define DH_   64
#define BH_   64          // B_*H_
#define M_    25096       // B_*SEQ_
#define MPAD_ 25216       // storage pad (197*128)
#define DIM_  512
#define NQKV_ 1536
#define NCH_  13          // CLS split-K chunks of 256 keys

typedef _Float16 half8_t __attribute__((ext_vector_type(8)));
typedef _Float16 half4_t __attribute__((ext_vector_type(4)));
typedef float f32x4 __attribute__((ext_vector_type(4)));

// workspace byte offsets
#define XH_OFF     ((size_t)0)                    // [MPAD_][512] f16   25,821,184
#define WQKVT_OFF  ((size_t)25821184)             // [1536][512] f16     1,572,864
#define WOUTT_OFF  ((size_t)27394048)             // [512][512]  f16       524,288
#define QH_OFF     ((size_t)27918336)             // [64][3137][64] f16 25,698,304
#define KH_OFF     ((size_t)53616640)
#define VH_OFF     ((size_t)79314944)
#define ATTNH_OFF  ((size_t)105013248)            // [MPAD_][512] f16   25,821,184
// CLS partials alias the xh region (dead after qkv_gemm; rewritten each call)
#define CLSP_OFF   XH_OFF                         // 64*13*72 floats = 239,616 B

__device__ __forceinline__ void load_lds16(const _Float16* g, _Float16* l) {
  __builtin_amdgcn_global_load_lds(
      (const __attribute__((address_space(1))) void*)g,
      (__attribute__((address_space(3))) void*)l, 16, 0, 0);
}

// bijective XCD-chunk swizzle (m204)
__device__ __forceinline__ int xcd_swz(int orig, int nwg) {
  int q = nwg >> 3, r = nwg & 7;
  int x = orig & 7, j = orig >> 3;
  return (x < r ? x * (q + 1) : r * (q + 1) + (x - r) * q) + j;
}

// ---------------------------------------------------------------------------
// conversion kernels
// ---------------------------------------------------------------------------
__global__ __launch_bounds__(256) void convert_x_kernel(
    const float* __restrict__ x, _Float16* __restrict__ xh) {
  const size_t n8 = (size_t)M_ * DIM_ / 8;
  for (size_t i = (size_t)blockIdx.x * blockDim.x + threadIdx.x; i < n8;
       i += (size_t)gridDim.x * blockDim.x) {
    float4 a = ((const float4*)x)[2 * i];
    float4 b = ((const float4*)x)[2 * i + 1];
    half8_t h;
    h[0] = (_Float16)a.x; h[1] = (_Float16)a.y; h[2] = (_Float16)a.z; h[3] = (_Float16)a.w;
    h[4] = (_Float16)b.x; h[5] = (_Float16)b.y; h[6] = (_Float16)b.z; h[7] = (_Float16)b.w;
    ((half8_t*)xh)[i] = h;
  }
}

// both weights: [512][C] fp32 -> [C][512] fp16 in one launch
__global__ __launch_bounds__(256) void transpose_conv2_kernel(
    const float* __restrict__ wqkv, _Float16* __restrict__ wqkvT,
    const float* __restrict__ wout, _Float16* __restrict__ woutT) {
  __shared__ float tile[32][33];
  int by = blockIdx.y;
  const float* in; _Float16* out; int C;
  if (by < 48) { in = wqkv; out = wqkvT; C = NQKV_; }
  else         { in = wout; out = woutT; C = DIM_;  by -= 48; }
  const int r0 = blockIdx.x * 32, c0 = by * 32;
  const int lr = threadIdx.x >> 5, lc = threadIdx.x & 31;
#pragma unroll
  for (int p = 0; p < 4; ++p) {
    int r = p * 8 + lr;
    tile[r][lc] = in[(size_t)(r0 + r) * C + c0 + lc];
  }
  __syncthreads();
#pragma unroll
  for (int p = 0; p < 4; ++p) {
    int rr = p * 8 + lr;
    out[(size_t)(c0 + rr) * DIM_ + r0 + lc] = (_Float16)tile[lc][rr];
  }
}

// ---------------------------------------------------------------------------
// shared f16 MFMA mainloop: 128x128 tile, BK=64, 256 threads (4 waves 2x2).
// LDS XOR-swizzled: linear global_load_lds dest + pre-swizzled global source
// col; frag reads XOR (row&7)<<3.
// ---------------------------------------------------------------------------
__device__ __forceinline__ void gemm_mainloop_f16(
    const _Float16* __restrict__ A, const _Float16* __restrict__ Bt,
    int m0, int n0, _Float16* As, _Float16* Bs, f32x4 acc[4][4]) {
  const int tid = threadIdx.x;
  const int w = tid >> 6, lane = tid & 63;
  const int wr = w >> 1, wc = w & 1;
  const int lrow = lane & 15;
  const int g = lane >> 4;
  const int sw = lane & 7;

  const int srow = lane >> 3;
  const int scol = ((lane & 7) ^ srow) << 3;

  for (int k0 = 0; k0 < DIM_; k0 += 64) {
#pragma unroll
    for (int i = 0; i < 4; ++i) {
      int c = w * 4 + i;
      int r = c * 8 + srow;
      load_lds16(A + (size_t)(m0 + r) * DIM_ + k0 + scol, As + c * 512);
      load_lds16(Bt + (size_t)(n0 + r) * DIM_ + k0 + scol, Bs + c * 512);
    }
    __syncthreads();

#pragma unroll
    for (int kk = 0; kk < 2; ++kk) {
      const int kf = ((kk * 4 + g) ^ sw) << 3;
      half8_t a[4], b[4];
#pragma unroll
      for (int m = 0; m < 4; ++m)
        a[m] = *(const half8_t*)(As + (wr * 64 + m * 16 + lrow) * 64 + kf);
#pragma unroll
      for (int n = 0; n < 4; ++n)
        b[n] = *(const half8_t*)(Bs + (wc * 64 + n * 16 + lrow) * 64 + kf);
#pragma unroll
      for (int m = 0; m < 4; ++m)
#pragma unroll
        for (int n = 0; n < 4; ++n)
          acc[m][n] = __builtin_amdgcn_mfma_f32_16x16x32_f16(a[m], b[n], acc[m][n], 0, 0, 0);
    }
    __syncthreads();
  }
}

// ---------------------------------------------------------------------------
// K1: qkv = xh @ WqkvT^T, scatter into qh/kh/vh [bh][t][64] f16, q scaled.
// Staged coalesced epilogue (LDS transpose, 128B row stores).
// ---------------------------------------------------------------------------
__global__ __launch_bounds__(256) void qkv_gemm_kernel(
    const _Float16* __restrict__ xh, const _Float16* __restrict__ wqkvT,
    _Float16* __restrict__ qh, _Float16* __restrict__ kh, _Float16* __restrict__ vh) {
  __shared__ _Float16 As[128 * 64];
  __shared__ _Float16 Bs[128 * 64];
  const int nwg = 197 * 12;
  const int lin = xcd_swz(blockIdx.x, nwg);
  const int mb = lin / 12, nb = lin - mb * 12;
  const int m0 = mb * 128, n0 = nb * 128;

  f32x4 acc[4][4];
#pragma unroll
  for (int m = 0; m < 4; ++m)
#pragma unroll
    for (int n = 0; n < 4; ++n) acc[m][n] = (f32x4)0.f;

  gemm_mainloop_f16(xh, wqkvT, m0, n0, As, Bs, acc);
  // mainloop ends with __syncthreads(): safe to reuse As/Bs as staging.

  const int tid = threadIdx.x;
  const int w = tid >> 6, lane = tid & 63;
  const int wr = w >> 1, wc = w & 1;
  const int g = lane >> 4, lrow = lane & 15;

  _Float16* stg = (w < 2) ? (As + w * 4096) : (Bs + (w - 2) * 4096);
  const int gcb0 = n0 + wc * 64;            // 64-aligned -> one head chunk
  const int which = gcb0 >> 9;
  const int h = (gcb0 >> 6) & 7;
  const float scale = (which == 0) ? 0.125f : 1.0f;
  _Float16* dst = (which == 0) ? qh : (which == 1) ? kh : vh;

#pragma unroll
  for (int m = 0; m < 4; ++m)
#pragma unroll
    for (int n = 0; n < 4; ++n)
#pragma unroll
      for (int j = 0; j < 4; ++j) {
        int row = m * 16 + g * 4 + j;
        int col = n * 16 + lrow;
        int slot = (col >> 3) ^ (row & 7);
        stg[row * 64 + slot * 8 + (col & 7)] = (_Float16)(acc[m][n][j] * scale);
      }
  asm volatile("s_waitcnt lgkmcnt(0)" ::: "memory");
  __builtin_amdgcn_sched_barrier(0);

  const int rl = lane >> 3, cs = lane & 7;
#pragma unroll
  for (int rr = 0; rr < 8; ++rr) {
    int row = rr * 8 + rl;
    int grow = m0 + wr * 64 + row;
    if (grow < M_) {
      int b = grow / SEQ_;
      int t = grow - b * SEQ_;
      half8_t v = *(const half8_t*)(stg + row * 64 + ((cs ^ (row & 7)) << 3));
      *(half8_t*)(dst + ((size_t)(b * H_ + h) * SEQ_ + t) * DH_ + cs * 8) = v;
    }
  }
}

// ---------------------------------------------------------------------------
// K4: out = attnh @ WoutT^T + bout (fp32 out).
// ---------------------------------------------------------------------------
__global__ __launch_bounds__(256) void out_gemm_kernel(
    const _Float16* __restrict__ attnh, const _Float16* __restrict__ woutT,
    const float* __restrict__ bias, float* __restrict__ out) {
  __shared__ _Float16 As[128 * 64];
  __shared__ _Float16 Bs[128 * 64];
  const int nwg = 197 * 4;
  const int lin = xcd_swz(blockIdx.x, nwg);
  const int mb = lin >> 2, nb = lin & 3;
  const int m0 = mb * 128, n0 = nb * 128;

  f32x4 acc[4][4];
#pragma unroll
  for (int m = 0; m < 4; ++m)
#pragma unroll
    for (int n = 0; n < 4; ++n) acc[m][n] = (f32x4)0.f;

  gemm_mainloop_f16(attnh, woutT, m0, n0, As, Bs, acc);

  const int tid = threadIdx.x;
  const int w = tid >> 6, lane = tid & 63;
  const int wr = w >> 1, wc = w & 1;
#pragma unroll
  for (int n = 0; n < 4; ++n) {
    const int gcol = n0 + wc * 64 + n * 16 + (lane & 15);
    const float bv = bias[gcol];
#pragma unroll
    for (int m = 0; m < 4; ++m)
#pragma unroll
      for (int j = 0; j < 4; ++j) {
        int grow = m0 + wr * 64 + m * 16 + (lane >> 4) * 4 + j;
        if (grow < M_) out[(size_t)grow * DIM_ + gcol] = acc[m][n][j] + bv;
      }
  }
}

// ---------------------------------------------------------------------------
// K2+K3: blocks 0..1023 = frame attention (one per (bh,frame), 4 waves MFMA);
// blocks 1024..1855 = CLS split-K partials (one per (bh, 256-key chunk)).
// ---------------------------------------------------------------------------
__global__ __launch_bounds__(256) void attn_kernel(
    const _Float16* __restrict__ qh, const _Float16* __restrict__ kh,
    const _Float16* __restrict__ vh, _Float16* __restrict__ attnh,
    float* __restrict__ clsp) {
  __shared__ _Float16 VT[64 * 232];      // frame: V^T [d][key]
  __shared__ _Float16 Pb[4][16 * 232];   // frame: per-wave P [q][key]
  const int bx = blockIdx.x;
  const int tid = threadIdx.x;

  if (bx >= BH_ * F_) {
    // ---------------- CLS split-K partial ----------------
    const int pb = bx - BH_ * F_;        // 0..831
    const int bh = pb / NCH_, ch = pb - bh * NCH_;
    const int j0 = ch * 256;
    const int nk = min(256, SEQ_ - j0);  // 256 or 65
    float* qs  = (float*)Pb;             // [64]
    float* pp  = qs + 64;                // [256]
    float* red = pp + 256;               // [256]

    if (tid < 64) qs[tid] = (float)qh[(size_t)bh * SEQ_ * DH_ + tid];
    __syncthreads();

    float sc = -1e30f;
    if (tid < nk) {
      const half8_t* kr = (const half8_t*)(kh + ((size_t)bh * SEQ_ + j0 + tid) * DH_);
      float s = 0.f;
#pragma unroll
      for (int i = 0; i < 8; ++i) {
        half8_t kk = kr[i];
#pragma unroll
        for (int u = 0; u < 8; ++u) s += qs[8 * i + u] * (float)kk[u];
      }
      sc = s;
    }
    red[tid] = sc; __syncthreads();
    for (int st = 128; st > 0; st >>= 1) {
      if (tid < st) red[tid] = fmaxf(red[tid], red[tid + st]);
      __syncthreads();
    }
    const float m = red[0]; __syncthreads();

    float p = (tid < nk) ? __expf(sc - m) : 0.f;
    pp[tid] = p;
    red[tid] = p; __syncthreads();
    for (int st = 128; st > 0; st >>= 1) {
      if (tid < st) red[tid] += red[tid + st];
      __syncthreads();
    }
    const float l = red[0]; __syncthreads();

    const int d = tid & 63, grp = tid >> 6;
    float a = 0.f;
#pragma unroll 4
    for (int u = 0; u < 64; ++u) {
      int jj = grp * 64 + u;
      int jc = min(j0 + jj, SEQ_ - 1);
      a += pp[jj] * (float)vh[((size_t)bh * SEQ_ + jc) * DH_ + d];
    }
    red[tid] = a; __syncthreads();
    if (tid < 64) {
      float asum = red[tid] + red[64 + tid] + red[128 + tid] + red[192 + tid];
      float* P = clsp + (size_t)(bh * NCH_ + ch) * 72;
      P[tid] = asum;
      if (tid == 0) { P[64] = m; P[65] = l; }
    }
    return;
  }

  // ---------------- frame attention ----------------
  const int bh = bx >> 4, fi = bx & 15;
  const int b = bh >> 3, h = bh & 7;
  const int w = tid >> 6, lane = tid & 63;
  const int g = lane >> 4, lc = lane & 15;
  _Float16* Pw = Pb[w];

  const size_t base = (size_t)bh * SEQ_ * DH_;

  // stage V^T (transpose-scatter), valid keys 0..196
  for (int item = tid; item < 197 * 8; item += 256) {
    int c8 = item / 197;
    int key = item - c8 * 197;
    int rowtok = (key == 0) ? 0 : fi * NP_ + key;
    half8_t hv = *(const half8_t*)(vh + base + (size_t)rowtok * DH_ + c8 * 8);
#pragma unroll
    for (int u = 0; u < 8; ++u) VT[(c8 * 8 + u) * 232 + key] = hv[u];
  }
  for (int idx = tid; idx < 64 * 35; idx += 256) {
    int d = idx / 35;
    VT[d * 232 + 197 + (idx - d * 35)] = (_Float16)0.f;
  }
#pragma unroll
  for (int z = 0; z < 4; ++z) {
    int idx = z * 64 + lane;
    Pw[(idx >> 4) * 232 + 208 + (idx & 15)] = (_Float16)0.f;
  }
  __syncthreads();

  const f32x4 zero4 = (f32x4)0.f;

  for (int qt = w; qt < 13; qt += 4) {
    int qq = qt * 16 + lc;
    int qtok = 1 + fi * NP_ + min(qq, NP_ - 1);
    const _Float16* qp = qh + base + (size_t)qtok * DH_ + g * 8;
    half8_t qb0 = *(const half8_t*)(qp);
    half8_t qb1 = *(const half8_t*)(qp + 32);

    f32x4 st[13];
#pragma unroll
    for (int t = 0; t < 13; ++t) {
      int key = t * 16 + lc;
      int rowtok = (key == 0) ? 0 : fi * NP_ + min(key, NP_);
      const _Float16* kp = kh + base + (size_t)rowtok * DH_ + g * 8;
      half8_t ka0 = *(const half8_t*)(kp);
      half8_t ka1 = *(const half8_t*)(kp + 32);
      st[t] = __builtin_amdgcn_mfma_f32_16x16x32_f16(ka0, qb0, zero4, 0, 0, 0);
      st[t] = __builtin_amdgcn_mfma_f32_16x16x32_f16(ka1, qb1, st[t], 0, 0, 0);
    }

    float mx = -1e30f;
#pragma unroll
    for (int t = 0; t < 13; ++t)
#pragma unroll
      for (int j = 0; j < 4; ++j) {
        int key = t * 16 + g * 4 + j;
        if (key >= 197) st[t][j] = -1e30f;
        mx = fmaxf(mx, st[t][j]);
      }
    mx = fmaxf(mx, __shfl_xor(mx, 16));
    mx = fmaxf(mx, __shfl_xor(mx, 32));
    float l = 0.f;
#pragma unroll
    for (int t = 0; t < 13; ++t)
#pragma unroll
      for (int j = 0; j < 4; ++j) {
        float p = __expf(st[t][j] - mx);
        st[t][j] = p;
        l += p;
      }
    l += __shfl_xor(l, 16);
    l += __shfl_xor(l, 32);
    const float inv = 1.f / l;

#pragma unroll
    for (int t = 0; t < 13; ++t) {
      half4_t hp;
#pragma unroll
      for (int j = 0; j < 4; ++j) hp[j] = (_Float16)(st[t][j] * inv);
      *(half4_t*)(Pw + lc * 232 + t * 16 + g * 4) = hp;
    }

    f32x4 o[4];
#pragma unroll
    for (int dt = 0; dt < 4; ++dt) o[dt] = zero4;
#pragma unroll
    for (int c = 0; c < 7; ++c) {
      half8_t pa = *(const half8_t*)(Pw + lc * 232 + c * 32 + g * 8);
#pragma unroll
      for (int dt = 0; dt < 4; ++dt) {
        half8_t vb = *(const half8_t*)(VT + (dt * 16 + lc) * 232 + c * 32 + g * 8);
        o[dt] = __builtin_amdgcn_mfma_f32_16x16x32_f16(pa, vb, o[dt], 0, 0, 0);
      }
    }

#pragma unroll
    for (int dt = 0; dt < 4; ++dt)
#pragma unroll
      for (int j = 0; j < 4; ++j) {
        int q = qt * 16 + g * 4 + j;
        if (q < NP_) {
          int tok = 1 + fi * NP_ + q;
          attnh[((size_t)(b * SEQ_) + tok) * DIM_ + h * DH_ + dt * 16 + lc] =
              (_Float16)o[dt][j];
        }
      }
  }
}

// ---------------------------------------------------------------------------
// CLS combine: merge 13 split-K partials per (b,h) -> attnh CLS row.
// ---------------------------------------------------------------------------
__global__ __launch_bounds__(64) void cls_combine_kernel(
    const float* __restrict__ clsp, _Float16* __restrict__ attnh) {
  const int bh = blockIdx.x;
  const int b = bh >> 3, h = bh & 7;
  const int d = threadIdx.x;
  const float* P = clsp + (size_t)bh * NCH_ * 72;

  float m = -1e30f;
#pragma unroll
  for (int c = 0; c < NCH_; ++c) m = fmaxf(m, P[c * 72 + 64]);
  float l = 0.f, o = 0.f;
#pragma unroll
  for (int c = 0; c < NCH_; ++c) {
    float wgt = __expf(P[c * 72 + 64] - m);
    l += P[c * 72 + 65] * wgt;
    o += P[c * 72 + d] * wgt;
  }
  attnh[(size_t)(b * SEQ_) * DIM_ + h * DH_ + d] = (_Float16)(o / l);
}

// ---------------------------------------------------------------------------
extern "C" void kernel_launch(void* const* d_in, const int* in_sizes, int n_in,
                              void* d_out, int out_size, void* d_ws, size_t ws_size,
                              hipStream_t stream) {
  (void)in_sizes; (void)n_in; (void)out_size; (void)ws_size;
  const float* x    = (const float*)d_in[0];
  const float* wqkv = (const float*)d_in[1];
  const float* wout = (const float*)d_in[2];
  const float* bout = (const float*)d_in[3];
  char* ws = (char*)d_ws;
  _Float16* xh    = (_Float16*)(ws + XH_OFF);
  _Float16* wqkvT = (_Float16*)(ws + WQKVT_OFF);
  _Float16* woutT = (_Float16*)(ws + WOUTT_OFF);
  _Float16* qh    = (_Float16*)(ws + QH_OFF);
  _Float16* kh    = (_Float16*)(ws + KH_OFF);
  _Float16* vh    = (_Float16*)(ws + VH_OFF);
  _Float16* attnh = (_Float16*)(ws + ATTNH_OFF);
  float*    clsp  = (float*)(ws + CLSP_OFF);   // aliases xh (dead after qkv)
  float* out = (float*)d_out;

  convert_x_kernel<<<2048, 256, 0, stream>>>(x, xh);
  {
    dim3 g(16, 64);  // 48 blocks-y for Wqkv, 16 for Wout
    transpose_conv2_kernel<<<g, 256, 0, stream>>>(wqkv, wqkvT, wout, woutT);
  }

  qkv_gemm_kernel<<<197 * 12, 256, 0, stream>>>(xh, wqkvT, qh, kh, vh);

  attn_kernel<<<BH_ * F_ + BH_ * NCH_, 256, 0, stream>>>(qh, kh, vh, attnh, clsp);
  cls_combine_kernel<<<BH_, 64, 0, stream>>>(clsp, attnh);

  out_gemm_kernel<<<197 * 4, 256, 0, stream>>>(attnh, woutT, bout, out);
}

// Round 10
// 174.341 us; speedup vs baseline: 1.8338x; 1.1838x over previous
//
#include <hip/hip_runtime.h>
#include <hip/hip_bf16.h>

// Problem constants
#define B_    8
#define F_    16
#define NP_   196
#define SEQ_  3137        // 1 + F_*NP_
#define H_    8
#define DH_   64
#define BH_   64          // B_*H_
#define M_    25096       // B_*SEQ_
#define MPAD_ 25216       // storage pad (197*128)
#define DIM_  512
#define NQKV_ 1536
#define NCH_  13          // CLS split-K chunks of 256 keys

typedef _Float16 half8_t __attribute__((ext_vector_type(8)));
typedef _Float16 half4_t __attribute__((ext_vector_type(4)));
typedef float f32x4 __attribute__((ext_vector_type(4)));

// workspace byte offsets
#define XH_OFF     ((size_t)0)                    // [MPAD_][512] f16   25,821,184
#define WQKVT_OFF  ((size_t)25821184)             // [1536][512] f16     1,572,864
#define WOUTT_OFF  ((size_t)27394048)             // [512][512]  f16       524,288
#define QH_OFF     ((size_t)27918336)             // [64][3137][64] f16 25,698,304
#define KH_OFF     ((size_t)53616640)
#define VH_OFF     ((size_t)79314944)
#define ATTNH_OFF  ((size_t)105013248)            // [MPAD_][512] f16   25,821,184
// CLS partials alias the xh region (dead after qkv_gemm; rewritten each call)
#define CLSP_OFF   XH_OFF                         // 64*13*72 floats = 239,616 B

__device__ __forceinline__ void load_lds16(const _Float16* g, _Float16* l) {
  __builtin_amdgcn_global_load_lds(
      (const __attribute__((address_space(1))) void*)g,
      (__attribute__((address_space(3))) void*)l, 16, 0, 0);
}

// bijective XCD-chunk swizzle (m204)
__device__ __forceinline__ int xcd_swz(int orig, int nwg) {
  int q = nwg >> 3, r = nwg & 7;
  int x = orig & 7, j = orig >> 3;
  return (x < r ? x * (q + 1) : r * (q + 1) + (x - r) * q) + j;
}

// ---------------------------------------------------------------------------
// conversion kernels
// ---------------------------------------------------------------------------
__global__ __launch_bounds__(256) void convert_x_kernel(
    const float* __restrict__ x, _Float16* __restrict__ xh) {
  const size_t n8 = (size_t)M_ * DIM_ / 8;
  for (size_t i = (size_t)blockIdx.x * blockDim.x + threadIdx.x; i < n8;
       i += (size_t)gridDim.x * blockDim.x) {
    float4 a = ((const float4*)x)[2 * i];
    float4 b = ((const float4*)x)[2 * i + 1];
    half8_t h;
    h[0] = (_Float16)a.x; h[1] = (_Float16)a.y; h[2] = (_Float16)a.z; h[3] = (_Float16)a.w;
    h[4] = (_Float16)b.x; h[5] = (_Float16)b.y; h[6] = (_Float16)b.z; h[7] = (_Float16)b.w;
    ((half8_t*)xh)[i] = h;
  }
}

// both weights: [512][C] fp32 -> [C][512] fp16 in one launch
__global__ __launch_bounds__(256) void transpose_conv2_kernel(
    const float* __restrict__ wqkv, _Float16* __restrict__ wqkvT,
    const float* __restrict__ wout, _Float16* __restrict__ woutT) {
  __shared__ float tile[32][33];
  int by = blockIdx.y;
  const float* in; _Float16* out; int C;
  if (by < 48) { in = wqkv; out = wqkvT; C = NQKV_; }
  else         { in = wout; out = woutT; C = DIM_;  by -= 48; }
  const int r0 = blockIdx.x * 32, c0 = by * 32;
  const int lr = threadIdx.x >> 5, lc = threadIdx.x & 31;
#pragma unroll
  for (int p = 0; p < 4; ++p) {
    int r = p * 8 + lr;
    tile[r][lc] = in[(size_t)(r0 + r) * C + c0 + lc];
  }
  __syncthreads();
#pragma unroll
  for (int p = 0; p < 4; ++p) {
    int rr = p * 8 + lr;
    out[(size_t)(c0 + rr) * DIM_ + r0 + lc] = (_Float16)tile[lc][rr];
  }
}

// ---------------------------------------------------------------------------
// shared f16 MFMA mainloop: 128x128 tile, BK=64, 256 threads (4 waves 2x2).
// LDS XOR-swizzled: linear global_load_lds dest + pre-swizzled global source
// col; frag reads XOR (row&7)<<3.
// ---------------------------------------------------------------------------
__device__ __forceinline__ void gemm_mainloop_f16(
    const _Float16* __restrict__ A, const _Float16* __restrict__ Bt,
    int m0, int n0, _Float16* As, _Float16* Bs, f32x4 acc[4][4]) {
  const int tid = threadIdx.x;
  const int w = tid >> 6, lane = tid & 63;
  const int wr = w >> 1, wc = w & 1;
  const int lrow = lane & 15;
  const int g = lane >> 4;
  const int sw = lane & 7;

  const int srow = lane >> 3;
  const int scol = ((lane & 7) ^ srow) << 3;

  for (int k0 = 0; k0 < DIM_; k0 += 64) {
#pragma unroll
    for (int i = 0; i < 4; ++i) {
      int c = w * 4 + i;
      int r = c * 8 + srow;
      load_lds16(A + (size_t)(m0 + r) * DIM_ + k0 + scol, As + c * 512);
      load_lds16(Bt + (size_t)(n0 + r) * DIM_ + k0 + scol, Bs + c * 512);
    }
    __syncthreads();

#pragma unroll
    for (int kk = 0; kk < 2; ++kk) {
      const int kf = ((kk * 4 + g) ^ sw) << 3;
      half8_t a[4], b[4];
#pragma unroll
      for (int m = 0; m < 4; ++m)
        a[m] = *(const half8_t*)(As + (wr * 64 + m * 16 + lrow) * 64 + kf);
#pragma unroll
      for (int n = 0; n < 4; ++n)
        b[n] = *(const half8_t*)(Bs + (wc * 64 + n * 16 + lrow) * 64 + kf);
#pragma unroll
      for (int m = 0; m < 4; ++m)
#pragma unroll
        for (int n = 0; n < 4; ++n)
          acc[m][n] = __builtin_amdgcn_mfma_f32_16x16x32_f16(a[m], b[n], acc[m][n], 0, 0, 0);
    }
    __syncthreads();
  }
}

// ---------------------------------------------------------------------------
// K1: qkv = xh @ WqkvT^T, scatter into qh/kh/vh [bh][t][64] f16, q scaled.
// Staged coalesced epilogue (LDS transpose, 128B row stores).
// ---------------------------------------------------------------------------
__global__ __launch_bounds__(256) void qkv_gemm_kernel(
    const _Float16* __restrict__ xh, const _Float16* __restrict__ wqkvT,
    _Float16* __restrict__ qh, _Float16* __restrict__ kh, _Float16* __restrict__ vh) {
  __shared__ _Float16 As[128 * 64];
  __shared__ _Float16 Bs[128 * 64];
  const int nwg = 197 * 12;
  const int lin = xcd_swz(blockIdx.x, nwg);
  const int mb = lin / 12, nb = lin - mb * 12;
  const int m0 = mb * 128, n0 = nb * 128;

  f32x4 acc[4][4];
#pragma unroll
  for (int m = 0; m < 4; ++m)
#pragma unroll
    for (int n = 0; n < 4; ++n) acc[m][n] = (f32x4)0.f;

  gemm_mainloop_f16(xh, wqkvT, m0, n0, As, Bs, acc);
  // mainloop ends with __syncthreads(): safe to reuse As/Bs as staging.

  const int tid = threadIdx.x;
  const int w = tid >> 6, lane = tid & 63;
  const int wr = w >> 1, wc = w & 1;
  const int g = lane >> 4, lrow = lane & 15;

  _Float16* stg = (w < 2) ? (As + w * 4096) : (Bs + (w - 2) * 4096);
  const int gcb0 = n0 + wc * 64;            // 64-aligned -> one head chunk
  const int which = gcb0 >> 9;
  const int h = (gcb0 >> 6) & 7;
  const float scale = (which == 0) ? 0.125f : 1.0f;
  _Float16* dst = (which == 0) ? qh : (which == 1) ? kh : vh;

#pragma unroll
  for (int m = 0; m < 4; ++m)
#pragma unroll
    for (int n = 0; n < 4; ++n)
#pragma unroll
      for (int j = 0; j < 4; ++j) {
        int row = m * 16 + g * 4 + j;
        int col = n * 16 + lrow;
        int slot = (col >> 3) ^ (row & 7);
        stg[row * 64 + slot * 8 + (col & 7)] = (_Float16)(acc[m][n][j] * scale);
      }
  asm volatile("s_waitcnt lgkmcnt(0)" ::: "memory");
  __builtin_amdgcn_sched_barrier(0);

  const int rl = lane >> 3, cs = lane & 7;
#pragma unroll
  for (int rr = 0; rr < 8; ++rr) {
    int row = rr * 8 + rl;
    int grow = m0 + wr * 64 + row;
    if (grow < M_) {
      int b = grow / SEQ_;
      int t = grow - b * SEQ_;
      half8_t v = *(const half8_t*)(stg + row * 64 + ((cs ^ (row & 7)) << 3));
      *(half8_t*)(dst + ((size_t)(b * H_ + h) * SEQ_ + t) * DH_ + cs * 8) = v;
    }
  }
}

// ---------------------------------------------------------------------------
// K4: out = attnh @ WoutT^T + bout (fp32 out).
// ---------------------------------------------------------------------------
__global__ __launch_bounds__(256) void out_gemm_kernel(
    const _Float16* __restrict__ attnh, const _Float16* __restrict__ woutT,
    const float* __restrict__ bias, float* __restrict__ out) {
  __shared__ _Float16 As[128 * 64];
  __shared__ _Float16 Bs[128 * 64];
  const int nwg = 197 * 4;
  const int lin = xcd_swz(blockIdx.x, nwg);
  const int mb = lin >> 2, nb = lin & 3;
  const int m0 = mb * 128, n0 = nb * 128;

  f32x4 acc[4][4];
#pragma unroll
  for (int m = 0; m < 4; ++m)
#pragma unroll
    for (int n = 0; n < 4; ++n) acc[m][n] = (f32x4)0.f;

  gemm_mainloop_f16(attnh, woutT, m0, n0, As, Bs, acc);

  const int tid = threadIdx.x;
  const int w = tid >> 6, lane = tid & 63;
  const int wr = w >> 1, wc = w & 1;
#pragma unroll
  for (int n = 0; n < 4; ++n) {
    const int gcol = n0 + wc * 64 + n * 16 + (lane & 15);
    const float bv = bias[gcol];
#pragma unroll
    for (int m = 0; m < 4; ++m)
#pragma unroll
      for (int j = 0; j < 4; ++j) {
        int grow = m0 + wr * 64 + m * 16 + (lane >> 4) * 4 + j;
        if (grow < M_) out[(size_t)grow * DIM_ + gcol] = acc[m][n][j] + bv;
      }
  }
}

// ---------------------------------------------------------------------------
// K2+K3: blocks 0..1023 = frame attention (one per (bh,frame), 4 waves MFMA,
// K bulk-staged via global_load_lds, split-PV P buffers);
// blocks 1024..1855 = CLS split-K partials (one per (bh, 256-key chunk)).
// LDS: KL 26.6KB + VT 29.7KB + Pb 17.4KB = 72KB -> 2 blocks/CU.
// ---------------------------------------------------------------------------
__global__ __launch_bounds__(256) void attn_kernel(
    const _Float16* __restrict__ qh, const _Float16* __restrict__ kh,
    const _Float16* __restrict__ vh, _Float16* __restrict__ attnh,
    float* __restrict__ clsp) {
  __shared__ _Float16 KL[208 * 64];      // frame: K rows, XOR-swizzled cols
  __shared__ _Float16 VT[64 * 232];      // frame: V^T [d][key]
  __shared__ _Float16 Pb[4 * 16 * 136];  // frame: per-wave split P
  const int bx = blockIdx.x;
  const int tid = threadIdx.x;

  if (bx >= BH_ * F_) {
    // ---------------- CLS split-K partial ----------------
    const int pb = bx - BH_ * F_;        // 0..831
    const int bh = pb / NCH_, ch = pb - bh * NCH_;
    const int j0 = ch * 256;
    const int nk = min(256, SEQ_ - j0);  // 256 or 65
    float* qs  = (float*)Pb;             // [64]
    float* pp  = qs + 64;                // [256]
    float* red = pp + 256;               // [256]

    if (tid < 64) qs[tid] = (float)qh[(size_t)bh * SEQ_ * DH_ + tid];
    __syncthreads();

    float sc = -1e30f;
    if (tid < nk) {
      const half8_t* kr = (const half8_t*)(kh + ((size_t)bh * SEQ_ + j0 + tid) * DH_);
      float s = 0.f;
#pragma unroll
      for (int i = 0; i < 8; ++i) {
        half8_t kk = kr[i];
#pragma unroll
        for (int u = 0; u < 8; ++u) s += qs[8 * i + u] * (float)kk[u];
      }
      sc = s;
    }
    red[tid] = sc; __syncthreads();
    for (int st = 128; st > 0; st >>= 1) {
      if (tid < st) red[tid] = fmaxf(red[tid], red[tid + st]);
      __syncthreads();
    }
    const float m = red[0]; __syncthreads();

    float p = (tid < nk) ? __expf(sc - m) : 0.f;
    pp[tid] = p;
    red[tid] = p; __syncthreads();
    for (int st = 128; st > 0; st >>= 1) {
      if (tid < st) red[tid] += red[tid + st];
      __syncthreads();
    }
    const float l = red[0]; __syncthreads();

    const int d = tid & 63, grp = tid >> 6;
    float a = 0.f;
#pragma unroll 4
    for (int u = 0; u < 64; ++u) {
      int jj = grp * 64 + u;
      int jc = min(j0 + jj, SEQ_ - 1);
      a += pp[jj] * (float)vh[((size_t)bh * SEQ_ + jc) * DH_ + d];
    }
    red[tid] = a; __syncthreads();
    if (tid < 64) {
      float asum = red[tid] + red[64 + tid] + red[128 + tid] + red[192 + tid];
      float* P = clsp + (size_t)(bh * NCH_ + ch) * 72;
      P[tid] = asum;
      if (tid == 0) { P[64] = m; P[65] = l; }
    }
    return;
  }

  // ---------------- frame attention ----------------
  const int bh = bx >> 4, fi = bx & 15;
  const int b = bh >> 3, h = bh & 7;
  const int w = tid >> 6, lane = tid & 63;
  const int g = lane >> 4, lc = lane & 15;
  _Float16* Pw = Pb + w * (16 * 136);

  const size_t base = (size_t)bh * SEQ_ * DH_;

  // hoisted Q loads (all 4 qt candidates for this wave)
  half8_t qb0[4], qb1[4];
#pragma unroll
  for (int it = 0; it < 4; ++it) {
    int qq = min((w + it * 4) * 16 + lc, NP_ - 1);
    const _Float16* qp = qh + base + (size_t)(1 + fi * NP_ + qq) * DH_ + g * 8;
    qb0[it] = *(const half8_t*)(qp);
    qb1[it] = *(const half8_t*)(qp + 32);
  }

  // bulk K staging: 208 rows x 64 f16 via global_load_lds, source col
  // pre-swizzled (cg ^ (row&7)), LDS dest linear (rule #21).
  for (int i = 0; i < 7; ++i) {
    int gran = i * 256 + tid;
    if (gran < 1664) {
      int row = gran >> 3, cg = gran & 7;
      int rowtok = (row == 0) ? 0 : fi * NP_ + min(row, NP_);
      load_lds16(kh + base + (size_t)rowtok * DH_ + ((cg ^ (row & 7)) << 3),
                 KL + (i * 256 + (tid & 192)) * 8);
    }
  }

  // stage V^T (transpose-scatter), valid keys 0..196
  for (int item = tid; item < 197 * 8; item += 256) {
    int c8 = item / 197;
    int key = item - c8 * 197;
    int rowtok = (key == 0) ? 0 : fi * NP_ + key;
    half8_t hv = *(const half8_t*)(vh + base + (size_t)rowtok * DH_ + c8 * 8);
#pragma unroll
    for (int u = 0; u < 8; ++u) VT[(c8 * 8 + u) * 232 + key] = hv[u];
  }
  for (int idx = tid; idx < 64 * 35; idx += 256) {
    int d = idx / 35;
    VT[d * 232 + 197 + (idx - d * 35)] = (_Float16)0.f;
  }
  __syncthreads();   // drains vmcnt+lgkmcnt: K, V staging complete

  const f32x4 zero4 = (f32x4)0.f;

#pragma unroll
  for (int it = 0; it < 4; ++it) {
    const int qt = w + it * 4;
    if (qt < 13) {
      // QK^T from LDS K (XOR-swizzled reads, 2-way = free)
      f32x4 st[13];
#pragma unroll
      for (int t = 0; t < 13; ++t) {
        int key = t * 16 + lc;
        const _Float16* kp = KL + key * 64;
        half8_t ka0 = *(const half8_t*)(kp + ((g ^ (key & 7)) << 3));
        half8_t ka1 = *(const half8_t*)(kp + (((4 + g) ^ (key & 7)) << 3));
        st[t] = __builtin_amdgcn_mfma_f32_16x16x32_f16(ka0, qb0[it], zero4, 0, 0, 0);
        st[t] = __builtin_amdgcn_mfma_f32_16x16x32_f16(ka1, qb1[it], st[t], 0, 0, 0);
      }

      float mx = -1e30f;
#pragma unroll
      for (int t = 0; t < 13; ++t)
#pragma unroll
        for (int j = 0; j < 4; ++j) {
          int key = t * 16 + g * 4 + j;
          if (key >= 197) st[t][j] = -1e30f;
          mx = fmaxf(mx, st[t][j]);
        }
      mx = fmaxf(mx, __shfl_xor(mx, 16));
      mx = fmaxf(mx, __shfl_xor(mx, 32));
      float l = 0.f;
#pragma unroll
      for (int t = 0; t < 13; ++t)
#pragma unroll
        for (int j = 0; j < 4; ++j) {
          float p = __expf(st[t][j] - mx);
          st[t][j] = p;
          l += p;
        }
      l += __shfl_xor(l, 16);
      l += __shfl_xor(l, 32);
      const float inv = 1.f / l;

      f32x4 o[4];
#pragma unroll
      for (int dt = 0; dt < 4; ++dt) o[dt] = zero4;

      // ---- half A: P tiles 0..7 (keys 0..127), stride 136 ----
#pragma unroll
      for (int t = 0; t < 8; ++t) {
        half4_t hp;
#pragma unroll
        for (int j = 0; j < 4; ++j) hp[j] = (_Float16)(st[t][j] * inv);
        *(half4_t*)(Pw + lc * 136 + t * 16 + g * 4) = hp;
      }
#pragma unroll
      for (int c = 0; c < 4; ++c) {
        half8_t pa = *(const half8_t*)(Pw + lc * 136 + c * 32 + g * 8);
#pragma unroll
        for (int dt = 0; dt < 4; ++dt) {
          half8_t vb = *(const half8_t*)(VT + (dt * 16 + lc) * 232 + c * 32 + g * 8);
          o[dt] = __builtin_amdgcn_mfma_f32_16x16x32_f16(pa, vb, o[dt], 0, 0, 0);
        }
      }

      // ---- half B: P tiles 8..12 + zero tile (keys 128..223), stride 104 ----
#pragma unroll
      for (int t = 8; t < 13; ++t) {
        half4_t hp;
#pragma unroll
        for (int j = 0; j < 4; ++j) hp[j] = (_Float16)(st[t][j] * inv);
        *(half4_t*)(Pw + lc * 104 + (t - 8) * 16 + g * 4) = hp;
      }
      {
        half4_t hz;
#pragma unroll
        for (int j = 0; j < 4; ++j) hz[j] = (_Float16)0.f;
        *(half4_t*)(Pw + lc * 104 + 80 + g * 4) = hz;   // keys 208..223
      }
#pragma unroll
      for (int c = 4; c < 7; ++c) {
        half8_t pa = *(const half8_t*)(Pw + lc * 104 + (c - 4) * 32 + g * 8);
#pragma unroll
        for (int dt = 0; dt < 4; ++dt) {
          half8_t vb = *(const half8_t*)(VT + (dt * 16 + lc) * 232 + c * 32 + g * 8);
          o[dt] = __builtin_amdgcn_mfma_f32_16x16x32_f16(pa, vb, o[dt], 0, 0, 0);
        }
      }

#pragma unroll
      for (int dt = 0; dt < 4; ++dt)
#pragma unroll
        for (int j = 0; j < 4; ++j) {
          int q = qt * 16 + g * 4 + j;
          if (q < NP_) {
            int tok = 1 + fi * NP_ + q;
            attnh[((size_t)(b * SEQ_) + tok) * DIM_ + h * DH_ + dt * 16 + lc] =
                (_Float16)o[dt][j];
          }
        }
    }
  }
}

// ---------------------------------------------------------------------------
// CLS combine: merge 13 split-K partials per (b,h) -> attnh CLS row.
// ---------------------------------------------------------------------------
__global__ __launch_bounds__(64) void cls_combine_kernel(
    const float* __restrict__ clsp, _Float16* __restrict__ attnh) {
  const int bh = blockIdx.x;
  const int b = bh >> 3, h = bh & 7;
  const int d = threadIdx.x;
  const float* P = clsp + (size_t)bh * NCH_ * 72;

  float m = -1e30f;
#pragma unroll
  for (int c = 0; c < NCH_; ++c) m = fmaxf(m, P[c * 72 + 64]);
  float l = 0.f, o = 0.f;
#pragma unroll
  for (int c = 0; c < NCH_; ++c) {
    float wgt = __expf(P[c * 72 + 64] - m);
    l += P[c * 72 + 65] * wgt;
    o += P[c * 72 + d] * wgt;
  }
  attnh[(size_t)(b * SEQ_) * DIM_ + h * DH_ + d] = (_Float16)(o / l);
}

// ---------------------------------------------------------------------------
extern "C" void kernel_launch(void* const* d_in, const int* in_sizes, int n_in,
                              void* d_out, int out_size, void* d_ws, size_t ws_size,
                              hipStream_t stream) {
  (void)in_sizes; (void)n_in; (void)out_size; (void)ws_size;
  const float* x    = (const float*)d_in[0];
  const float* wqkv = (const float*)d_in[1];
  const float* wout = (const float*)d_in[2];
  const float* bout = (const float*)d_in[3];
  char* ws = (char*)d_ws;
  _Float16* xh    = (_Float16*)(ws + XH_OFF);
  _Float16* wqkvT = (_Float16*)(ws + WQKVT_OFF);
  _Float16* woutT = (_Float16*)(ws + WOUTT_OFF);
  _Float16* qh    = (_Float16*)(ws + QH_OFF);
  _Float16* kh    = (_Float16*)(ws + KH_OFF);
  _Float16* vh    = (_Float16*)(ws + VH_OFF);
  _Float16* attnh = (_Float16*)(ws + ATTNH_OFF);
  float*    clsp  = (float*)(ws + CLSP_OFF);   // aliases xh (dead after qkv)
  float* out = (float*)d_out;

  convert_x_kernel<<<2048, 256, 0, stream>>>(x, xh);
  {
    dim3 g(16, 64);  // 48 blocks-y for Wqkv, 16 for Wout
    transpose_conv2_kernel<<<g, 256, 0, stream>>>(wqkv, wqkvT, wout, woutT);
  }

  qkv_gemm_kernel<<<197 * 12, 256, 0, stream>>>(xh, wqkvT, qh, kh, vh);

  attn_kernel<<<BH_ * F_ + BH_ * NCH_, 256, 0, stream>>>(qh, kh, vh, attnh, clsp);
  cls_combine_kernel<<<BH_, 64, 0, stream>>>(clsp, attnh);

  out_gemm_kernel<<<197 * 4, 256, 0, stream>>>(attnh, woutT, bout, out);
}

// Round 11
// 170.463 us; speedup vs baseline: 1.8755x; 1.0228x over previous
//
#include <hip/hip_runtime.h>
#include <hip/hip_bf16.h>

// Problem constants
#define B_    8
#define F_    16
#define NP_   196
#define SEQ_  3137        // 1 + F_*NP_
#define H_    8
#define DH_   64
#define BH_   64          // B_*H_
#define M_    25096       // B_*SEQ_
#define MPAD_ 25216       // storage pad (197*128)
#define DIM_  512
#define NQKV_ 1536
#define NCH_  13          // CLS split-K chunks of 256 keys

typedef _Float16 half8_t __attribute__((ext_vector_type(8)));
typedef _Float16 half4_t __attribute__((ext_vector_type(4)));
typedef float f32x4 __attribute__((ext_vector_type(4)));

// workspace byte offsets
#define XH_OFF     ((size_t)0)                    // [MPAD_][512] f16   25,821,184
#define WQKVT_OFF  ((size_t)25821184)             // [1536][512] f16     1,572,864
#define WOUTT_OFF  ((size_t)27394048)             // [512][512]  f16       524,288
#define QH_OFF     ((size_t)27918336)             // [64][3137][64] f16 25,698,304
#define KH_OFF     ((size_t)53616640)
#define VH_OFF     ((size_t)79314944)
#define ATTNH_OFF  ((size_t)105013248)            // [MPAD_][512] f16   25,821,184
// CLS partials alias the xh region (dead after qkv_gemm; rewritten each call)
#define CLSP_OFF   XH_OFF                         // 64*13*72 floats = 239,616 B

__device__ __forceinline__ void load_lds16(const _Float16* g, _Float16* l) {
  __builtin_amdgcn_global_load_lds(
      (const __attribute__((address_space(1))) void*)g,
      (__attribute__((address_space(3))) void*)l, 16, 0, 0);
}

// bijective XCD-chunk swizzle (m204)
__device__ __forceinline__ int xcd_swz(int orig, int nwg) {
  int q = nwg >> 3, r = nwg & 7;
  int x = orig & 7, j = orig >> 3;
  return (x < r ? x * (q + 1) : r * (q + 1) + (x - r) * q) + j;
}

// ---------------------------------------------------------------------------
// conversion kernels
// ---------------------------------------------------------------------------
__global__ __launch_bounds__(256) void convert_x_kernel(
    const float* __restrict__ x, _Float16* __restrict__ xh) {
  const size_t n8 = (size_t)M_ * DIM_ / 8;
  for (size_t i = (size_t)blockIdx.x * blockDim.x + threadIdx.x; i < n8;
       i += (size_t)gridDim.x * blockDim.x) {
    float4 a = ((const float4*)x)[2 * i];
    float4 b = ((const float4*)x)[2 * i + 1];
    half8_t h;
    h[0] = (_Float16)a.x; h[1] = (_Float16)a.y; h[2] = (_Float16)a.z; h[3] = (_Float16)a.w;
    h[4] = (_Float16)b.x; h[5] = (_Float16)b.y; h[6] = (_Float16)b.z; h[7] = (_Float16)b.w;
    ((half8_t*)xh)[i] = h;
  }
}

// both weights: [512][C] fp32 -> [C][512] fp16 in one launch
__global__ __launch_bounds__(256) void transpose_conv2_kernel(
    const float* __restrict__ wqkv, _Float16* __restrict__ wqkvT,
    const float* __restrict__ wout, _Float16* __restrict__ woutT) {
  __shared__ float tile[32][33];
  int by = blockIdx.y;
  const float* in; _Float16* out; int C;
  if (by < 48) { in = wqkv; out = wqkvT; C = NQKV_; }
  else         { in = wout; out = woutT; C = DIM_;  by -= 48; }
  const int r0 = blockIdx.x * 32, c0 = by * 32;
  const int lr = threadIdx.x >> 5, lc = threadIdx.x & 31;
#pragma unroll
  for (int p = 0; p < 4; ++p) {
    int r = p * 8 + lr;
    tile[r][lc] = in[(size_t)(r0 + r) * C + c0 + lc];
  }
  __syncthreads();
#pragma unroll
  for (int p = 0; p < 4; ++p) {
    int rr = p * 8 + lr;
    out[(size_t)(c0 + rr) * DIM_ + r0 + lc] = (_Float16)tile[lc][rr];
  }
}

// ---------------------------------------------------------------------------
// shared f16 MFMA mainloop: 128x128 tile, BK=64, 256 threads (4 waves 2x2).
// ---------------------------------------------------------------------------
__device__ __forceinline__ void gemm_mainloop_f16(
    const _Float16* __restrict__ A, const _Float16* __restrict__ Bt,
    int m0, int n0, _Float16* As, _Float16* Bs, f32x4 acc[4][4]) {
  const int tid = threadIdx.x;
  const int w = tid >> 6, lane = tid & 63;
  const int wr = w >> 1, wc = w & 1;
  const int lrow = lane & 15;
  const int g = lane >> 4;
  const int sw = lane & 7;

  const int srow = lane >> 3;
  const int scol = ((lane & 7) ^ srow) << 3;

  for (int k0 = 0; k0 < DIM_; k0 += 64) {
#pragma unroll
    for (int i = 0; i < 4; ++i) {
      int c = w * 4 + i;
      int r = c * 8 + srow;
      load_lds16(A + (size_t)(m0 + r) * DIM_ + k0 + scol, As + c * 512);
      load_lds16(Bt + (size_t)(n0 + r) * DIM_ + k0 + scol, Bs + c * 512);
    }
    __syncthreads();

#pragma unroll
    for (int kk = 0; kk < 2; ++kk) {
      const int kf = ((kk * 4 + g) ^ sw) << 3;
      half8_t a[4], b[4];
#pragma unroll
      for (int m = 0; m < 4; ++m)
        a[m] = *(const half8_t*)(As + (wr * 64 + m * 16 + lrow) * 64 + kf);
#pragma unroll
      for (int n = 0; n < 4; ++n)
        b[n] = *(const half8_t*)(Bs + (wc * 64 + n * 16 + lrow) * 64 + kf);
#pragma unroll
      for (int m = 0; m < 4; ++m)
#pragma unroll
        for (int n = 0; n < 4; ++n)
          acc[m][n] = __builtin_amdgcn_mfma_f32_16x16x32_f16(a[m], b[n], acc[m][n], 0, 0, 0);
    }
    __syncthreads();
  }
}

// ---------------------------------------------------------------------------
// K1: qkv = xh @ WqkvT^T, scatter into qh/kh/vh [bh][t][64] f16, q scaled.
// ---------------------------------------------------------------------------
__global__ __launch_bounds__(256) void qkv_gemm_kernel(
    const _Float16* __restrict__ xh, const _Float16* __restrict__ wqkvT,
    _Float16* __restrict__ qh, _Float16* __restrict__ kh, _Float16* __restrict__ vh) {
  __shared__ _Float16 As[128 * 64];
  __shared__ _Float16 Bs[128 * 64];
  const int nwg = 197 * 12;
  const int lin = xcd_swz(blockIdx.x, nwg);
  const int mb = lin / 12, nb = lin - mb * 12;
  const int m0 = mb * 128, n0 = nb * 128;

  f32x4 acc[4][4];
#pragma unroll
  for (int m = 0; m < 4; ++m)
#pragma unroll
    for (int n = 0; n < 4; ++n) acc[m][n] = (f32x4)0.f;

  gemm_mainloop_f16(xh, wqkvT, m0, n0, As, Bs, acc);

  const int tid = threadIdx.x;
  const int w = tid >> 6, lane = tid & 63;
  const int wr = w >> 1, wc = w & 1;
  const int g = lane >> 4, lrow = lane & 15;

  _Float16* stg = (w < 2) ? (As + w * 4096) : (Bs + (w - 2) * 4096);
  const int gcb0 = n0 + wc * 64;
  const int which = gcb0 >> 9;
  const int h = (gcb0 >> 6) & 7;
  const float scale = (which == 0) ? 0.125f : 1.0f;
  _Float16* dst = (which == 0) ? qh : (which == 1) ? kh : vh;

#pragma unroll
  for (int m = 0; m < 4; ++m)
#pragma unroll
    for (int n = 0; n < 4; ++n)
#pragma unroll
      for (int j = 0; j < 4; ++j) {
        int row = m * 16 + g * 4 + j;
        int col = n * 16 + lrow;
        int slot = (col >> 3) ^ (row & 7);
        stg[row * 64 + slot * 8 + (col & 7)] = (_Float16)(acc[m][n][j] * scale);
      }
  asm volatile("s_waitcnt lgkmcnt(0)" ::: "memory");
  __builtin_amdgcn_sched_barrier(0);

  const int rl = lane >> 3, cs = lane & 7;
#pragma unroll
  for (int rr = 0; rr < 8; ++rr) {
    int row = rr * 8 + rl;
    int grow = m0 + wr * 64 + row;
    if (grow < M_) {
      int b = grow / SEQ_;
      int t = grow - b * SEQ_;
      half8_t v = *(const half8_t*)(stg + row * 64 + ((cs ^ (row & 7)) << 3));
      *(half8_t*)(dst + ((size_t)(b * H_ + h) * SEQ_ + t) * DH_ + cs * 8) = v;
    }
  }
}

// ---------------------------------------------------------------------------
// K4: out = attnh @ WoutT^T + bout (fp32 out).
// ---------------------------------------------------------------------------
__global__ __launch_bounds__(256) void out_gemm_kernel(
    const _Float16* __restrict__ attnh, const _Float16* __restrict__ woutT,
    const float* __restrict__ bias, float* __restrict__ out) {
  __shared__ _Float16 As[128 * 64];
  __shared__ _Float16 Bs[128 * 64];
  const int nwg = 197 * 4;
  const int lin = xcd_swz(blockIdx.x, nwg);
  const int mb = lin >> 2, nb = lin & 3;
  const int m0 = mb * 128, n0 = nb * 128;

  f32x4 acc[4][4];
#pragma unroll
  for (int m = 0; m < 4; ++m)
#pragma unroll
    for (int n = 0; n < 4; ++n) acc[m][n] = (f32x4)0.f;

  gemm_mainloop_f16(attnh, woutT, m0, n0, As, Bs, acc);

  const int tid = threadIdx.x;
  const int w = tid >> 6, lane = tid & 63;
  const int wr = w >> 1, wc = w & 1;
#pragma unroll
  for (int n = 0; n < 4; ++n) {
    const int gcol = n0 + wc * 64 + n * 16 + (lane & 15);
    const float bv = bias[gcol];
#pragma unroll
    for (int m = 0; m < 4; ++m)
#pragma unroll
      for (int j = 0; j < 4; ++j) {
        int grow = m0 + wr * 64 + m * 16 + (lane >> 4) * 4 + j;
        if (grow < M_) out[(size_t)grow * DIM_ + gcol] = acc[m][n][j] + bv;
      }
  }
}

// ---------------------------------------------------------------------------
// K2+K3: blocks 0..1023 = frame attention; 1024..1855 = CLS split-K partials.
// All global reads coalesced via global_load_lds (XOR-swizzled source cols,
// linear LDS dest — rule #21); V^T built by LDS->LDS transpose.
// SMEM carve (f16): frame: KL[13312] VT[14848] Pb[8704] (tmp aliases Pb);
//                   cls:   Kc[16384] + floats after.
// ---------------------------------------------------------------------------
__global__ __launch_bounds__(256) void attn_kernel(
    const _Float16* __restrict__ qh, const _Float16* __restrict__ kh,
    const _Float16* __restrict__ vh, _Float16* __restrict__ attnh,
    float* __restrict__ clsp) {
  __shared__ _Float16 SMEM[36864];     // 73,728 B
  const int bx = blockIdx.x;
  const int tid = threadIdx.x;

  if (bx >= BH_ * F_) {
    // ---------------- CLS split-K partial ----------------
    const int pb = bx - BH_ * F_;        // 0..831
    const int bh = pb / NCH_, ch = pb - bh * NCH_;
    const int j0 = ch * 256;
    const int nk = min(256, SEQ_ - j0);  // 256 or 65
    _Float16* Kc = SMEM;                 // [256][64] swizzled
    float* qs  = (float*)(SMEM + 16384); // [64]
    float* pp  = qs + 64;                // [256]
    float* red = pp + 256;               // [256]
    const size_t kbase = (size_t)bh * SEQ_ * DH_;

    // coalesced K-chunk staging: 2048 16B chunks, 8 lanes/row (same line)
#pragma unroll
    for (int i = 0; i < 8; ++i) {
      int c = i * 256 + tid;
      int row = c >> 3, cg = c & 7;
      int grow = min(j0 + row, SEQ_ - 1);
      load_lds16(kh + kbase + (size_t)grow * DH_ + (((cg ^ (row & 7)) << 3)),
                 Kc + (i * 256 + (tid & 192)) * 8);
    }
    if (tid < 64) qs[tid] = (float)qh[kbase * 1 + (size_t)0 * DH_ + tid];  // q row 0
    __syncthreads();   // drains vmcnt: Kc ready

    // per-thread dot from LDS
    float sc;
    {
      float s = 0.f;
#pragma unroll
      for (int i = 0; i < 8; ++i) {
        half8_t kk = *(const half8_t*)(Kc + tid * 64 + (((i ^ (tid & 7)) << 3)));
#pragma unroll
        for (int u = 0; u < 8; ++u) s += qs[8 * i + u] * (float)kk[u];
      }
      sc = (tid < nk) ? s : -1e30f;
    }
    red[tid] = sc; __syncthreads();
    for (int st = 128; st > 0; st >>= 1) {
      if (tid < st) red[tid] = fmaxf(red[tid], red[tid + st]);
      __syncthreads();
    }
    const float m = red[0]; __syncthreads();

    float p = (tid < nk) ? __expf(sc - m) : 0.f;
    pp[tid] = p;
    red[tid] = p; __syncthreads();
    for (int st = 128; st > 0; st >>= 1) {
      if (tid < st) red[tid] += red[tid + st];
      __syncthreads();
    }
    const float l = red[0]; __syncthreads();

    const int d = tid & 63, grp = tid >> 6;
    float a = 0.f;
#pragma unroll 4
    for (int u = 0; u < 64; ++u) {
      int jj = grp * 64 + u;
      int jc = min(j0 + jj, SEQ_ - 1);
      a += pp[jj] * (float)vh[((size_t)bh * SEQ_ + jc) * DH_ + d];
    }
    red[tid] = a; __syncthreads();
    if (tid < 64) {
      float asum = red[tid] + red[64 + tid] + red[128 + tid] + red[192 + tid];
      float* P = clsp + (size_t)(bh * NCH_ + ch) * 72;
      P[tid] = asum;
      if (tid == 0) { P[64] = m; P[65] = l; }
    }
    return;
  }

  // ---------------- frame attention ----------------
  const int bh = bx >> 4, fi = bx & 15;
  const int b = bh >> 3, h = bh & 7;
  const int w = tid >> 6, lane = tid & 63;
  const int g = lane >> 4, lc = lane & 15;
  _Float16* KL = SMEM;                  // [208][64] swizzled
  _Float16* VT = SMEM + 13312;          // [64][232]
  _Float16* Pb = SMEM + 28160;          // 4 x [16][136]
  _Float16* tmp = Pb;                   // prologue alias: [104][64] swizzled
  _Float16* Pw = Pb + w * (16 * 136);

  const size_t base = (size_t)bh * SEQ_ * DH_;

  // hoisted Q loads (all 4 qt candidates for this wave)
  half8_t qb0[4], qb1[4];
#pragma unroll
  for (int it = 0; it < 4; ++it) {
    int qq = min((w + it * 4) * 16 + lc, NP_ - 1);
    const _Float16* qp = qh + base + (size_t)(1 + fi * NP_ + qq) * DH_ + g * 8;
    qb0[it] = *(const half8_t*)(qp);
    qb1[it] = *(const half8_t*)(qp + 32);
  }

  // bulk K staging: 208 rows x 64 f16, coalesced (8 lanes/row)
  for (int i = 0; i < 7; ++i) {
    int gran = i * 256 + tid;
    if (gran < 1664) {
      int row = gran >> 3, cg = gran & 7;
      int rowtok = (row == 0) ? 0 : fi * NP_ + min(row, NP_);
      load_lds16(kh + base + (size_t)rowtok * DH_ + ((cg ^ (row & 7)) << 3),
                 KL + (i * 256 + (tid & 192)) * 8);
    }
  }

  // V: stage row-major coalesced into tmp (104 rows/half), LDS-transpose to VT
#pragma unroll
  for (int half = 0; half < 2; ++half) {
    const int r0 = half * 104;
#pragma unroll
    for (int i = 0; i < 4; ++i) {
      int c = i * 256 + tid;
      if (c < 832) {
        int row = c >> 3, cg = c & 7;
        int gr = r0 + row;
        int rowtok = (gr == 0) ? 0 : fi * NP_ + min(gr, NP_);
        load_lds16(vh + base + (size_t)rowtok * DH_ + ((cg ^ (row & 7)) << 3),
                   tmp + (i * 256 + (tid & 192)) * 8);
      }
    }
    if (half == 1) {
      // zero VT cols 197..231 (disjoint from all transpose writes)
      for (int idx = tid; idx < 64 * 35; idx += 256) {
        int d = idx / 35;
        VT[d * 232 + 197 + (idx - d * 35)] = (_Float16)0.f;
      }
    }
    __syncthreads();   // drains staging into tmp (and K on first pass)
#pragma unroll
    for (int i = 0; i < 4; ++i) {
      int item = i * 256 + tid;
      if (item < 832) {
        int cg = item / 104;
        int key = item - cg * 104;     // lanes ~consecutive keys -> clean writes
        int gk = r0 + key;
        if (gk <= 196) {
          half8_t v = *(const half8_t*)(tmp + key * 64 + ((cg ^ (key & 7)) << 3));
#pragma unroll
          for (int u = 0; u < 8; ++u) VT[(cg * 8 + u) * 232 + gk] = v[u];
        }
      }
    }
    __syncthreads();   // transpose done before tmp reuse / P use
  }

  const f32x4 zero4 = (f32x4)0.f;

#pragma unroll
  for (int it = 0; it < 4; ++it) {
    const int qt = w + it * 4;
    if (qt < 13) {
      // QK^T from LDS K (XOR-swizzled reads)
      f32x4 st[13];
#pragma unroll
      for (int t = 0; t < 13; ++t) {
        int key = t * 16 + lc;
        const _Float16* kp = KL + key * 64;
        half8_t ka0 = *(const half8_t*)(kp + ((g ^ (key & 7)) << 3));
        half8_t ka1 = *(const half8_t*)(kp + (((4 + g) ^ (key & 7)) << 3));
        st[t] = __builtin_amdgcn_mfma_f32_16x16x32_f16(ka0, qb0[it], zero4, 0, 0, 0);
        st[t] = __builtin_amdgcn_mfma_f32_16x16x32_f16(ka1, qb1[it], st[t], 0, 0, 0);
      }

      float mx = -1e30f;
#pragma unroll
      for (int t = 0; t < 13; ++t)
#pragma unroll
        for (int j = 0; j < 4; ++j) {
          int key = t * 16 + g * 4 + j;
          if (key >= 197) st[t][j] = -1e30f;
          mx = fmaxf(mx, st[t][j]);
        }
      mx = fmaxf(mx, __shfl_xor(mx, 16));
      mx = fmaxf(mx, __shfl_xor(mx, 32));
      float l = 0.f;
#pragma unroll
      for (int t = 0; t < 13; ++t)
#pragma unroll
        for (int j = 0; j < 4; ++j) {
          float p = __expf(st[t][j] - mx);
          st[t][j] = p;
          l += p;
        }
      l += __shfl_xor(l, 16);
      l += __shfl_xor(l, 32);
      const float inv = 1.f / l;

      f32x4 o[4];
#pragma unroll
      for (int dt = 0; dt < 4; ++dt) o[dt] = zero4;

      // ---- half A: P tiles 0..7 (keys 0..127), stride 136 ----
#pragma unroll
      for (int t = 0; t < 8; ++t) {
        half4_t hp;
#pragma unroll
        for (int j = 0; j < 4; ++j) hp[j] = (_Float16)(st[t][j] * inv);
        *(half4_t*)(Pw + lc * 136 + t * 16 + g * 4) = hp;
      }
#pragma unroll
      for (int c = 0; c < 4; ++c) {
        half8_t pa = *(const half8_t*)(Pw + lc * 136 + c * 32 + g * 8);
#pragma unroll
        for (int dt = 0; dt < 4; ++dt) {
          half8_t vb = *(const half8_t*)(VT + (dt * 16 + lc) * 232 + c * 32 + g * 8);
          o[dt] = __builtin_amdgcn_mfma_f32_16x16x32_f16(pa, vb, o[dt], 0, 0, 0);
        }
      }

      // ---- half B: P tiles 8..12 + zero tile (keys 128..223), stride 104 ----
#pragma unroll
      for (int t = 8; t < 13; ++t) {
        half4_t hp;
#pragma unroll
        for (int j = 0; j < 4; ++j) hp[j] = (_Float16)(st[t][j] * inv);
        *(half4_t*)(Pw + lc * 104 + (t - 8) * 16 + g * 4) = hp;
      }
      {
        half4_t hz;
#pragma unroll
        for (int j = 0; j < 4; ++j) hz[j] = (_Float16)0.f;
        *(half4_t*)(Pw + lc * 104 + 80 + g * 4) = hz;   // keys 208..223
      }
#pragma unroll
      for (int c = 4; c < 7; ++c) {
        half8_t pa = *(const half8_t*)(Pw + lc * 104 + (c - 4) * 32 + g * 8);
#pragma unroll
        for (int dt = 0; dt < 4; ++dt) {
          half8_t vb = *(const half8_t*)(VT + (dt * 16 + lc) * 232 + c * 32 + g * 8);
          o[dt] = __builtin_amdgcn_mfma_f32_16x16x32_f16(pa, vb, o[dt], 0, 0, 0);
        }
      }

#pragma unroll
      for (int dt = 0; dt < 4; ++dt)
#pragma unroll
        for (int j = 0; j < 4; ++j) {
          int q = qt * 16 + g * 4 + j;
          if (q < NP_) {
            int tok = 1 + fi * NP_ + q;
            attnh[((size_t)(b * SEQ_) + tok) * DIM_ + h * DH_ + dt * 16 + lc] =
                (_Float16)o[dt][j];
          }
        }
    }
  }
}

// ---------------------------------------------------------------------------
// CLS combine: merge 13 split-K partials per (b,h) -> attnh CLS row.
// ---------------------------------------------------------------------------
__global__ __launch_bounds__(64) void cls_combine_kernel(
    const float* __restrict__ clsp, _Float16* __restrict__ attnh) {
  const int bh = blockIdx.x;
  const int b = bh >> 3, h = bh & 7;
  const int d = threadIdx.x;
  const float* P = clsp + (size_t)bh * NCH_ * 72;

  float m = -1e30f;
#pragma unroll
  for (int c = 0; c < NCH_; ++c) m = fmaxf(m, P[c * 72 + 64]);
  float l = 0.f, o = 0.f;
#pragma unroll
  for (int c = 0; c < NCH_; ++c) {
    float wgt = __expf(P[c * 72 + 64] - m);
    l += P[c * 72 + 65] * wgt;
    o += P[c * 72 + d] * wgt;
  }
  attnh[(size_t)(b * SEQ_) * DIM_ + h * DH_ + d] = (_Float16)(o / l);
}

// ---------------------------------------------------------------------------
extern "C" void kernel_launch(void* const* d_in, const int* in_sizes, int n_in,
                              void* d_out, int out_size, void* d_ws, size_t ws_size,
                              hipStream_t stream) {
  (void)in_sizes; (void)n_in; (void)out_size; (void)ws_size;
  const float* x    = (const float*)d_in[0];
  const float* wqkv = (const float*)d_in[1];
  const float* wout = (const float*)d_in[2];
  const float* bout = (const float*)d_in[3];
  char* ws = (char*)d_ws;
  _Float16* xh    = (_Float16*)(ws + XH_OFF);
  _Float16* wqkvT = (_Float16*)(ws + WQKVT_OFF);
  _Float16* woutT = (_Float16*)(ws + WOUTT_OFF);
  _Float16* qh    = (_Float16*)(ws + QH_OFF);
  _Float16* kh    = (_Float16*)(ws + KH_OFF);
  _Float16* vh    = (_Float16*)(ws + VH_OFF);
  _Float16* attnh = (_Float16*)(ws + ATTNH_OFF);
  float*    clsp  = (float*)(ws + CLSP_OFF);   // aliases xh (dead after qkv)
  float* out = (float*)d_out;

  convert_x_kernel<<<2048, 256, 0, stream>>>(x, xh);
  {
    dim3 g(16, 64);
    transpose_conv2_kernel<<<g, 256, 0, stream>>>(wqkv, wqkvT, wout, woutT);
  }

  qkv_gemm_kernel<<<197 * 12, 256, 0, stream>>>(xh, wqkvT, qh, kh, vh);

  attn_kernel<<<BH_ * F_ + BH_ * NCH_, 256, 0, stream>>>(qh, kh, vh, attnh, clsp);
  cls_combine_kernel<<<BH_, 64, 0, stream>>>(clsp, attnh);

  out_gemm_kernel<<<197 * 4, 256, 0, stream>>>(attnh, woutT, bout, out);
}

// Round 12
// 166.407 us; speedup vs baseline: 1.9212x; 1.0244x over previous
//
#include <hip/hip_runtime.h>
#include <hip/hip_bf16.h>

// Problem constants
#define B_    8
#define F_    16
#define NP_   196
#define SEQ_  3137        // 1 + F_*NP_
#define H_    8
#define DH_   64
#define BH_   64          // B_*H_
#define M_    25096       // B_*SEQ_
#define MPAD_ 25216       // storage pad (197*128)
#define DIM_  512
#define NQKV_ 1536

typedef _Float16 half8_t __attribute__((ext_vector_type(8)));
typedef _Float16 half4_t __attribute__((ext_vector_type(4)));
typedef float f32x4 __attribute__((ext_vector_type(4)));

// workspace byte offsets
#define XH_OFF     ((size_t)0)                    // [MPAD_][512] f16   25,821,184
#define WQKVT_OFF  ((size_t)25821184)             // [1536][512] f16     1,572,864
#define WOUTT_OFF  ((size_t)27394048)             // [512][512]  f16       524,288
#define QH_OFF     ((size_t)27918336)             // [64][3137][64] f16 25,698,304
#define KH_OFF     ((size_t)53616640)
#define VH_OFF     ((size_t)79314944)
#define ATTNH_OFF  ((size_t)105013248)            // [MPAD_][512] f16   25,821,184
// CLS partials alias the xh region (dead after qkv_gemm; rewritten each call)
#define CLSP_OFF   XH_OFF                         // 64*16*72 floats = 294,912 B

__device__ __forceinline__ void load_lds16(const _Float16* g, _Float16* l) {
  __builtin_amdgcn_global_load_lds(
      (const __attribute__((address_space(1))) void*)g,
      (__attribute__((address_space(3))) void*)l, 16, 0, 0);
}

// bijective XCD-chunk swizzle (m204)
__device__ __forceinline__ int xcd_swz(int orig, int nwg) {
  int q = nwg >> 3, r = nwg & 7;
  int x = orig & 7, j = orig >> 3;
  return (x < r ? x * (q + 1) : r * (q + 1) + (x - r) * q) + j;
}

// ---------------------------------------------------------------------------
// conversion kernels
// ---------------------------------------------------------------------------
__global__ __launch_bounds__(256) void convert_x_kernel(
    const float* __restrict__ x, _Float16* __restrict__ xh) {
  const size_t n8 = (size_t)M_ * DIM_ / 8;
  for (size_t i = (size_t)blockIdx.x * blockDim.x + threadIdx.x; i < n8;
       i += (size_t)gridDim.x * blockDim.x) {
    float4 a = ((const float4*)x)[2 * i];
    float4 b = ((const float4*)x)[2 * i + 1];
    half8_t h;
    h[0] = (_Float16)a.x; h[1] = (_Float16)a.y; h[2] = (_Float16)a.z; h[3] = (_Float16)a.w;
    h[4] = (_Float16)b.x; h[5] = (_Float16)b.y; h[6] = (_Float16)b.z; h[7] = (_Float16)b.w;
    ((half8_t*)xh)[i] = h;
  }
}

// both weights: [512][C] fp32 -> [C][512] fp16 in one launch
__global__ __launch_bounds__(256) void transpose_conv2_kernel(
    const float* __restrict__ wqkv, _Float16* __restrict__ wqkvT,
    const float* __restrict__ wout, _Float16* __restrict__ woutT) {
  __shared__ float tile[32][33];
  int by = blockIdx.y;
  const float* in; _Float16* out; int C;
  if (by < 48) { in = wqkv; out = wqkvT; C = NQKV_; }
  else         { in = wout; out = woutT; C = DIM_;  by -= 48; }
  const int r0 = blockIdx.x * 32, c0 = by * 32;
  const int lr = threadIdx.x >> 5, lc = threadIdx.x & 31;
#pragma unroll
  for (int p = 0; p < 4; ++p) {
    int r = p * 8 + lr;
    tile[r][lc] = in[(size_t)(r0 + r) * C + c0 + lc];
  }
  __syncthreads();
#pragma unroll
  for (int p = 0; p < 4; ++p) {
    int rr = p * 8 + lr;
    out[(size_t)(c0 + rr) * DIM_ + r0 + lc] = (_Float16)tile[lc][rr];
  }
}

// ---------------------------------------------------------------------------
// shared f16 MFMA mainloop: 128x128 tile, BK=64, 256 threads (4 waves 2x2).
// ---------------------------------------------------------------------------
__device__ __forceinline__ void gemm_mainloop_f16(
    const _Float16* __restrict__ A, const _Float16* __restrict__ Bt,
    int m0, int n0, _Float16* As, _Float16* Bs, f32x4 acc[4][4]) {
  const int tid = threadIdx.x;
  const int w = tid >> 6, lane = tid & 63;
  const int wr = w >> 1, wc = w & 1;
  const int lrow = lane & 15;
  const int g = lane >> 4;
  const int sw = lane & 7;

  const int srow = lane >> 3;
  const int scol = ((lane & 7) ^ srow) << 3;

  for (int k0 = 0; k0 < DIM_; k0 += 64) {
#pragma unroll
    for (int i = 0; i < 4; ++i) {
      int c = w * 4 + i;
      int r = c * 8 + srow;
      load_lds16(A + (size_t)(m0 + r) * DIM_ + k0 + scol, As + c * 512);
      load_lds16(Bt + (size_t)(n0 + r) * DIM_ + k0 + scol, Bs + c * 512);
    }
    __syncthreads();

#pragma unroll
    for (int kk = 0; kk < 2; ++kk) {
      const int kf = ((kk * 4 + g) ^ sw) << 3;
      half8_t a[4], b[4];
#pragma unroll
      for (int m = 0; m < 4; ++m)
        a[m] = *(const half8_t*)(As + (wr * 64 + m * 16 + lrow) * 64 + kf);
#pragma unroll
      for (int n = 0; n < 4; ++n)
        b[n] = *(const half8_t*)(Bs + (wc * 64 + n * 16 + lrow) * 64 + kf);
#pragma unroll
      for (int m = 0; m < 4; ++m)
#pragma unroll
        for (int n = 0; n < 4; ++n)
          acc[m][n] = __builtin_amdgcn_mfma_f32_16x16x32_f16(a[m], b[n], acc[m][n], 0, 0, 0);
    }
    __syncthreads();
  }
}

// ---------------------------------------------------------------------------
// K1: qkv = xh @ WqkvT^T, scatter into qh/kh/vh [bh][t][64] f16, q scaled.
// ---------------------------------------------------------------------------
__global__ __launch_bounds__(256) void qkv_gemm_kernel(
    const _Float16* __restrict__ xh, const _Float16* __restrict__ wqkvT,
    _Float16* __restrict__ qh, _Float16* __restrict__ kh, _Float16* __restrict__ vh) {
  __shared__ _Float16 As[128 * 64];
  __shared__ _Float16 Bs[128 * 64];
  const int nwg = 197 * 12;
  const int lin = xcd_swz(blockIdx.x, nwg);
  const int mb = lin / 12, nb = lin - mb * 12;
  const int m0 = mb * 128, n0 = nb * 128;

  f32x4 acc[4][4];
#pragma unroll
  for (int m = 0; m < 4; ++m)
#pragma unroll
    for (int n = 0; n < 4; ++n) acc[m][n] = (f32x4)0.f;

  gemm_mainloop_f16(xh, wqkvT, m0, n0, As, Bs, acc);

  const int tid = threadIdx.x;
  const int w = tid >> 6, lane = tid & 63;
  const int wr = w >> 1, wc = w & 1;
  const int g = lane >> 4, lrow = lane & 15;

  _Float16* stg = (w < 2) ? (As + w * 4096) : (Bs + (w - 2) * 4096);
  const int gcb0 = n0 + wc * 64;
  const int which = gcb0 >> 9;
  const int h = (gcb0 >> 6) & 7;
  const float scale = (which == 0) ? 0.125f : 1.0f;
  _Float16* dst = (which == 0) ? qh : (which == 1) ? kh : vh;

#pragma unroll
  for (int m = 0; m < 4; ++m)
#pragma unroll
    for (int n = 0; n < 4; ++n)
#pragma unroll
      for (int j = 0; j < 4; ++j) {
        int row = m * 16 + g * 4 + j;
        int col = n * 16 + lrow;
        int slot = (col >> 3) ^ (row & 7);
        stg[row * 64 + slot * 8 + (col & 7)] = (_Float16)(acc[m][n][j] * scale);
      }
  asm volatile("s_waitcnt lgkmcnt(0)" ::: "memory");
  __builtin_amdgcn_sched_barrier(0);

  const int rl = lane >> 3, cs = lane & 7;
#pragma unroll
  for (int rr = 0; rr < 8; ++rr) {
    int row = rr * 8 + rl;
    int grow = m0 + wr * 64 + row;
    if (grow < M_) {
      int b = grow / SEQ_;
      int t = grow - b * SEQ_;
      half8_t v = *(const half8_t*)(stg + row * 64 + ((cs ^ (row & 7)) << 3));
      *(half8_t*)(dst + ((size_t)(b * H_ + h) * SEQ_ + t) * DH_ + cs * 8) = v;
    }
  }
}

// ---------------------------------------------------------------------------
// K4: out = attnh @ WoutT^T + bout (fp32 out).
// ---------------------------------------------------------------------------
__global__ __launch_bounds__(256) void out_gemm_kernel(
    const _Float16* __restrict__ attnh, const _Float16* __restrict__ woutT,
    const float* __restrict__ bias, float* __restrict__ out) {
  __shared__ _Float16 As[128 * 64];
  __shared__ _Float16 Bs[128 * 64];
  const int nwg = 197 * 4;
  const int lin = xcd_swz(blockIdx.x, nwg);
  const int mb = lin >> 2, nb = lin & 3;
  const int m0 = mb * 128, n0 = nb * 128;

  f32x4 acc[4][4];
#pragma unroll
  for (int m = 0; m < 4; ++m)
#pragma unroll
    for (int n = 0; n < 4; ++n) acc[m][n] = (f32x4)0.f;

  gemm_mainloop_f16(attnh, woutT, m0, n0, As, Bs, acc);

  const int tid = threadIdx.x;
  const int w = tid >> 6, lane = tid & 63;
  const int wr = w >> 1, wc = w & 1;
#pragma unroll
  for (int n = 0; n < 4; ++n) {
    const int gcol = n0 + wc * 64 + n * 16 + (lane & 15);
    const float bv = bias[gcol];
#pragma unroll
    for (int m = 0; m < 4; ++m)
#pragma unroll
      for (int j = 0; j < 4; ++j) {
        int grow = m0 + wr * 64 + m * 16 + (lane >> 4) * 4 + j;
        if (grow < M_) out[(size_t)grow * DIM_ + gcol] = acc[m][n][j] + bv;
      }
  }
}

// ---------------------------------------------------------------------------
// K2+K3 fused: 1024 blocks, one per (bh, frame), 4 waves.
// Frame attention (MFMA) + CLS partial over this block's staged keys
// (fi=0 includes the CLS key; fi>0 masks it). CLS partial -> clsp[bh][fi].
// SMEM carve (f16): KL[13312] VT[14848] Pb[8704] (tmp + cls scratch alias Pb).
// ---------------------------------------------------------------------------
__global__ __launch_bounds__(256) void attn_kernel(
    const _Float16* __restrict__ qh, const _Float16* __restrict__ kh,
    const _Float16* __restrict__ vh, _Float16* __restrict__ attnh,
    float* __restrict__ clsp) {
  __shared__ _Float16 SMEM[36864];     // 73,728 B
  const int bx = blockIdx.x;
  const int tid = threadIdx.x;

  const int bh = bx >> 4, fi = bx & 15;
  const int b = bh >> 3, h = bh & 7;
  const int w = tid >> 6, lane = tid & 63;
  const int g = lane >> 4, lc = lane & 15;
  _Float16* KL = SMEM;                  // [208][64] swizzled
  _Float16* VT = SMEM + 13312;          // [64][232]
  _Float16* Pb = SMEM + 28160;          // 4 x [16][136]
  _Float16* tmp = Pb;                   // prologue alias: [104][64] swizzled
  _Float16* Pw = Pb + w * (16 * 136);

  const size_t base = (size_t)bh * SEQ_ * DH_;

  // hoisted Q loads (all 4 qt candidates for this wave)
  half8_t qb0[4], qb1[4];
#pragma unroll
  for (int it = 0; it < 4; ++it) {
    int qq = min((w + it * 4) * 16 + lc, NP_ - 1);
    const _Float16* qp = qh + base + (size_t)(1 + fi * NP_ + qq) * DH_ + g * 8;
    qb0[it] = *(const half8_t*)(qp);
    qb1[it] = *(const half8_t*)(qp + 32);
  }

  // bulk K staging: 208 rows x 64 f16, coalesced (8 lanes/row)
  for (int i = 0; i < 7; ++i) {
    int gran = i * 256 + tid;
    if (gran < 1664) {
      int row = gran >> 3, cg = gran & 7;
      int rowtok = (row == 0) ? 0 : fi * NP_ + min(row, NP_);
      load_lds16(kh + base + (size_t)rowtok * DH_ + ((cg ^ (row & 7)) << 3),
                 KL + (i * 256 + (tid & 192)) * 8);
    }
  }

  // V: stage row-major coalesced into tmp (104 rows/half), LDS-transpose to VT
#pragma unroll
  for (int half = 0; half < 2; ++half) {
    const int r0 = half * 104;
#pragma unroll
    for (int i = 0; i < 4; ++i) {
      int c = i * 256 + tid;
      if (c < 832) {
        int row = c >> 3, cg = c & 7;
        int gr = r0 + row;
        int rowtok = (gr == 0) ? 0 : fi * NP_ + min(gr, NP_);
        load_lds16(vh + base + (size_t)rowtok * DH_ + ((cg ^ (row & 7)) << 3),
                   tmp + (i * 256 + (tid & 192)) * 8);
      }
    }
    if (half == 1) {
      for (int idx = tid; idx < 64 * 35; idx += 256) {
        int d = idx / 35;
        VT[d * 232 + 197 + (idx - d * 35)] = (_Float16)0.f;
      }
    }
    __syncthreads();   // drains staging into tmp (and K on first pass)
#pragma unroll
    for (int i = 0; i < 4; ++i) {
      int item = i * 256 + tid;
      if (item < 832) {
        int cg = item / 104;
        int key = item - cg * 104;
        int gk = r0 + key;
        if (gk <= 196) {
          half8_t v = *(const half8_t*)(tmp + key * 64 + ((cg ^ (key & 7)) << 3));
#pragma unroll
          for (int u = 0; u < 8; ++u) VT[(cg * 8 + u) * 232 + gk] = v[u];
        }
      }
    }
    __syncthreads();   // transpose done before tmp reuse / P use
  }

  const f32x4 zero4 = (f32x4)0.f;

#pragma unroll
  for (int it = 0; it < 4; ++it) {
    const int qt = w + it * 4;
    if (qt < 13) {
      // QK^T from LDS K (XOR-swizzled reads)
      f32x4 st[13];
#pragma unroll
      for (int t = 0; t < 13; ++t) {
        int key = t * 16 + lc;
        const _Float16* kp = KL + key * 64;
        half8_t ka0 = *(const half8_t*)(kp + ((g ^ (key & 7)) << 3));
        half8_t ka1 = *(const half8_t*)(kp + (((4 + g) ^ (key & 7)) << 3));
        st[t] = __builtin_amdgcn_mfma_f32_16x16x32_f16(ka0, qb0[it], zero4, 0, 0, 0);
        st[t] = __builtin_amdgcn_mfma_f32_16x16x32_f16(ka1, qb1[it], st[t], 0, 0, 0);
      }

      float mx = -1e30f;
#pragma unroll
      for (int t = 0; t < 13; ++t)
#pragma unroll
        for (int j = 0; j < 4; ++j) {
          int key = t * 16 + g * 4 + j;
          if (key >= 197) st[t][j] = -1e30f;
          mx = fmaxf(mx, st[t][j]);
        }
      mx = fmaxf(mx, __shfl_xor(mx, 16));
      mx = fmaxf(mx, __shfl_xor(mx, 32));
      float l = 0.f;
#pragma unroll
      for (int t = 0; t < 13; ++t)
#pragma unroll
        for (int j = 0; j < 4; ++j) {
          float p = __expf(st[t][j] - mx);
          st[t][j] = p;
          l += p;
        }
      l += __shfl_xor(l, 16);
      l += __shfl_xor(l, 32);
      const float inv = 1.f / l;

      f32x4 o[4];
#pragma unroll
      for (int dt = 0; dt < 4; ++dt) o[dt] = zero4;

      // ---- half A: P tiles 0..7 (keys 0..127), stride 136 ----
#pragma unroll
      for (int t = 0; t < 8; ++t) {
        half4_t hp;
#pragma unroll
        for (int j = 0; j < 4; ++j) hp[j] = (_Float16)(st[t][j] * inv);
        *(half4_t*)(Pw + lc * 136 + t * 16 + g * 4) = hp;
      }
#pragma unroll
      for (int c = 0; c < 4; ++c) {
        half8_t pa = *(const half8_t*)(Pw + lc * 136 + c * 32 + g * 8);
#pragma unroll
        for (int dt = 0; dt < 4; ++dt) {
          half8_t vb = *(const half8_t*)(VT + (dt * 16 + lc) * 232 + c * 32 + g * 8);
          o[dt] = __builtin_amdgcn_mfma_f32_16x16x32_f16(pa, vb, o[dt], 0, 0, 0);
        }
      }

      // ---- half B: P tiles 8..12 + zero tile (keys 128..223), stride 104 ----
#pragma unroll
      for (int t = 8; t < 13; ++t) {
        half4_t hp;
#pragma unroll
        for (int j = 0; j < 4; ++j) hp[j] = (_Float16)(st[t][j] * inv);
        *(half4_t*)(Pw + lc * 104 + (t - 8) * 16 + g * 4) = hp;
      }
      {
        half4_t hz;
#pragma unroll
        for (int j = 0; j < 4; ++j) hz[j] = (_Float16)0.f;
        *(half4_t*)(Pw + lc * 104 + 80 + g * 4) = hz;   // keys 208..223
      }
#pragma unroll
      for (int c = 4; c < 7; ++c) {
        half8_t pa = *(const half8_t*)(Pw + lc * 104 + (c - 4) * 32 + g * 8);
#pragma unroll
        for (int dt = 0; dt < 4; ++dt) {
          half8_t vb = *(const half8_t*)(VT + (dt * 16 + lc) * 232 + c * 32 + g * 8);
          o[dt] = __builtin_amdgcn_mfma_f32_16x16x32_f16(pa, vb, o[dt], 0, 0, 0);
        }
      }

#pragma unroll
      for (int dt = 0; dt < 4; ++dt)
#pragma unroll
        for (int j = 0; j < 4; ++j) {
          int q = qt * 16 + g * 4 + j;
          if (q < NP_) {
            int tok = 1 + fi * NP_ + q;
            attnh[((size_t)(b * SEQ_) + tok) * DIM_ + h * DH_ + dt * 16 + lc] =
                (_Float16)o[dt][j];
          }
        }
    }
  }

  // ---------------- CLS partial over this block's staged keys ----------------
  __syncthreads();                       // all waves done with Pb; KL/VT stable
  float* qs  = (float*)Pb;               // [64]
  float* pp  = qs + 64;                  // [256]
  float* red = pp + 256;                 // [256]
  if (tid < 64) qs[tid] = (float)qh[base + tid];  // CLS q row (token 0, scaled)
  __syncthreads();

  const int kmin = (fi == 0) ? 0 : 1;    // CLS key only counted in block fi=0
  float sc = -1e30f;
  if (tid >= kmin && tid < 197) {
    float s = 0.f;
#pragma unroll
    for (int i = 0; i < 8; ++i) {
      half8_t kk = *(const half8_t*)(KL + tid * 64 + ((i ^ (tid & 7)) << 3));
#pragma unroll
      for (int u = 0; u < 8; ++u) s += qs[8 * i + u] * (float)kk[u];
    }
    sc = s;
  }
  red[tid] = sc; __syncthreads();
  for (int st = 128; st > 0; st >>= 1) {
    if (tid < st) red[tid] = fmaxf(red[tid], red[tid + st]);
    __syncthreads();
  }
  const float cm = red[0]; __syncthreads();

  float cp = (tid >= kmin && tid < 197) ? __expf(sc - cm) : 0.f;
  pp[tid] = cp;
  red[tid] = cp; __syncthreads();
  for (int st = 128; st > 0; st >>= 1) {
    if (tid < st) red[tid] += red[tid + st];
    __syncthreads();
  }
  const float clsum = red[0]; __syncthreads();

  const int d = tid & 63;                // grp == w (tid>>6)
  float a = 0.f;
#pragma unroll 4
  for (int u = 0; u < 64; ++u) {
    int k = w * 64 + u;
    if (k <= 196) a += pp[k] * (float)VT[d * 232 + k];
  }
  red[tid] = a; __syncthreads();
  if (tid < 64) {
    float asum = red[tid] + red[64 + tid] + red[128 + tid] + red[192 + tid];
    float* P = clsp + (size_t)(bh * 16 + fi) * 72;
    P[tid] = asum;
    if (tid == 0) { P[64] = cm; P[65] = clsum; }
  }
}

// ---------------------------------------------------------------------------
// CLS combine: merge 16 per-frame partials per (b,h) -> attnh CLS row.
// ---------------------------------------------------------------------------
__global__ __launch_bounds__(64) void cls_combine_kernel(
    const float* __restrict__ clsp, _Float16* __restrict__ attnh) {
  const int bh = blockIdx.x;
  const int b = bh >> 3, h = bh & 7;
  const int d = threadIdx.x;
  const float* P = clsp + (size_t)bh * 16 * 72;

  float m = -1e30f;
#pragma unroll
  for (int c = 0; c < 16; ++c) m = fmaxf(m, P[c * 72 + 64]);
  float l = 0.f, o = 0.f;
#pragma unroll
  for (int c = 0; c < 16; ++c) {
    float wgt = __expf(P[c * 72 + 64] - m);
    l += P[c * 72 + 65] * wgt;
    o += P[c * 72 + d] * wgt;
  }
  attnh[(size_t)(b * SEQ_) * DIM_ + h * DH_ + d] = (_Float16)(o / l);
}

// ---------------------------------------------------------------------------
extern "C" void kernel_launch(void* const* d_in, const int* in_sizes, int n_in,
                              void* d_out, int out_size, void* d_ws, size_t ws_size,
                              hipStream_t stream) {
  (void)in_sizes; (void)n_in; (void)out_size; (void)ws_size;
  const float* x    = (const float*)d_in[0];
  const float* wqkv = (const float*)d_in[1];
  const float* wout = (const float*)d_in[2];
  const float* bout = (const float*)d_in[3];
  char* ws = (char*)d_ws;
  _Float16* xh    = (_Float16*)(ws + XH_OFF);
  _Float16* wqkvT = (_Float16*)(ws + WQKVT_OFF);
  _Float16* woutT = (_Float16*)(ws + WOUTT_OFF);
  _Float16* qh    = (_Float16*)(ws + QH_OFF);
  _Float16* kh    = (_Float16*)(ws + KH_OFF);
  _Float16* vh    = (_Float16*)(ws + VH_OFF);
  _Float16* attnh = (_Float16*)(ws + ATTNH_OFF);
  float*    clsp  = (float*)(ws + CLSP_OFF);   // aliases xh (dead after qkv)
  float* out = (float*)d_out;

  convert_x_kernel<<<2048, 256, 0, stream>>>(x, xh);
  {
    dim3 g(16, 64);
    transpose_conv2_kernel<<<g, 256, 0, stream>>>(wqkv, wqkvT, wout, woutT);
  }

  qkv_gemm_kernel<<<197 * 12, 256, 0, stream>>>(xh, wqkvT, qh, kh, vh);

  attn_kernel<<<BH_ * F_, 256, 0, stream>>>(qh, kh, vh, attnh, clsp);
  cls_combine_kernel<<<BH_, 64, 0, stream>>>(clsp, attnh);

  out_gemm_kernel<<<197 * 4, 256, 0, stream>>>(attnh, woutT, bout, out);
}